// Round 10
// baseline (520.268 us; speedup 1.0000x reference)
//
#include <hip/hip_runtime.h>
#include <hip/hip_bf16.h>

#define H 4
#define D 32
#define F 128      // H*D
#define MAXDEG 64  // slot capacity per dst (Poisson(16), max ~45)
#define PF 16      // gather prefetch depth (rows in flight)
#define NBUCK 256  // dst-range buckets (direct-scan build)
#define BUCKW 196  // dst range width per bucket (256*196 = 50176 >= N)
#define GB    1563 // gemm blocks: 2 tiles/block over 3125 tiles
#define HXP   136  // LDS row stride (shorts), 16B-aligned rows

typedef __attribute__((ext_vector_type(8))) short bf16x8;  // 8 bf16 (4 VGPRs)
typedef __attribute__((ext_vector_type(4))) float f32x4;

__device__ __forceinline__ short f2bf(float v) {
    __hip_bfloat16 h = __float2bfloat16(v);   // RNE
    return *reinterpret_cast<short*>(&h);
}
__device__ __forceinline__ float bf2f(short s) {
    __hip_bfloat16 h = *reinterpret_cast<__hip_bfloat16*>(&s);
    return __bfloat162float(h);
}

// ===========================================================================
// W1 split piece (fp32 -> bf16 hi/lo), one part = 1/4 of W1.
// ===========================================================================
__device__ __forceinline__
void wconv_part(int part, const float* __restrict__ W1, short* __restrict__ W1hi,
                short* __restrict__ W1lo) {
    const int tid = threadIdx.x;
    const int base = part * (F * F / 4);     // 4096 elems per part
    for (int i = base + tid * 4; i < base + F * F / 4; i += 1024) {
        float4 v = *reinterpret_cast<const float4*>(W1 + i);
        float vv[4] = {v.x, v.y, v.z, v.w};
        short hs[4], ls[4];
#pragma unroll
        for (int j = 0; j < 4; ++j) {
            hs[j] = f2bf(vv[j]);
            ls[j] = f2bf(vv[j] - bf2f(hs[j]));
        }
        *reinterpret_cast<short4*>(W1hi + i) = make_short4(hs[0], hs[1], hs[2], hs[3]);
        *reinterpret_cast<short4*>(W1lo + i) = make_short4(ls[0], ls[1], ls[2], ls[3]);
    }
}

// ===========================================================================
// DIRECT-SCAN bucket build: block b scans ALL E dst entries (int4, range-
// compare — no divide) and slot-assigns its own ~3125 matching edges via LDS
// atomics on 196 counters. Replaces the two-phase bucketA/bucketB sort and
// its inter-kernel dependency (round-9 lesson: each removed dispatch
// boundary ≈ −8-10 µs). Scan traffic is L2-resident (6.4 MB shared by all
// 32 blocks/XCD) and runs concurrently with gemm0 in the same kernel.
// ===========================================================================
__device__ __forceinline__
void bucket_scan_body(int b, const int* __restrict__ ei, int E,
                      int* __restrict__ deg, unsigned short* __restrict__ ssrc2u,
                      int N, int* cnt, unsigned short* slots) {
    const int tid = threadIdx.x;
    if (tid < BUCKW) cnt[tid] = 0;
    __syncthreads();
    const int lo = b * BUCKW, hi = lo + BUCKW;
    for (int e = 4 * tid; e < E; e += 1024) {
        int4 dv = *reinterpret_cast<const int4*>(ei + E + e);
        int dd[4] = {dv.x, dv.y, dv.z, dv.w};
#pragma unroll
        for (int j = 0; j < 4; ++j) {
            int d = dd[j];
            if (d >= lo && d < hi) {
                int src  = ei[e + j];
                int slot = atomicAdd(&cnt[d - lo], 1);   // LDS atomic
                if (slot < MAXDEG)
                    slots[(d - lo) * MAXDEG + slot] = (unsigned short)src;
            }
        }
    }
    __syncthreads();
    // coalesced writeout into PADDED ssrc2u (NBUCK*BUCKW nodes)
    uint4* dst = reinterpret_cast<uint4*>(ssrc2u + (size_t)b * BUCKW * MAXDEG);
    const uint4* s4 = reinterpret_cast<const uint4*>(slots);
    for (int i = tid; i < BUCKW * MAXDEG / 8; i += 256)
        dst[i] = s4[i];
    if (tid < BUCKW) {
        int node = b * BUCKW + tid;
        if (node < N) deg[node] = cnt[tid];
    }
}

// ===========================================================================
// GEMM shared pieces. MFMA layouts (m89, proven in prior rounds):
// A[m=lane&15][k=q*8+j], B[n=lane&15][k=q*8+j], C col=lane&15, row=q*4+reg.
// ===========================================================================
__device__ __forceinline__
void bsetup_fp32(const float* __restrict__ W, int wave, int m, int q8,
                 bf16x8 Bhi[2][4], bf16x8 Blo[2][4]) {
#pragma unroll
    for (int j = 0; j < 2; ++j) {
        const int fout = wave * 32 + j * 16 + m;
#pragma unroll
        for (int kc = 0; kc < 4; ++kc) {
            const float* wp = W + (size_t)fout * F + kc * 32 + q8;
            float4 w0 = *reinterpret_cast<const float4*>(wp);
            float4 w1 = *reinterpret_cast<const float4*>(wp + 4);
            float wv[8] = {w0.x, w0.y, w0.z, w0.w, w1.x, w1.y, w1.z, w1.w};
#pragma unroll
            for (int t2 = 0; t2 < 8; ++t2) {
                short hh = f2bf(wv[t2]);
                Bhi[j][kc][t2] = hh;
                Blo[j][kc][t2] = f2bf(wv[t2] - bf2f(hh));
            }
        }
    }
}

__device__ __forceinline__
void bsetup_pre(const short* __restrict__ Whi, const short* __restrict__ Wlo,
                int wave, int m, int q8, bf16x8 Bhi[2][4], bf16x8 Blo[2][4]) {
#pragma unroll
    for (int j = 0; j < 2; ++j) {
        const int fout = wave * 32 + j * 16 + m;
#pragma unroll
        for (int kc = 0; kc < 4; ++kc) {
            Bhi[j][kc] = *reinterpret_cast<const bf16x8*>(Whi + (size_t)fout * F + kc * 32 + q8);
            Blo[j][kc] = *reinterpret_cast<const bf16x8*>(Wlo + (size_t)fout * F + kc * 32 + q8);
        }
    }
}

__device__ __forceinline__
void loadA_f32(const float* __restrict__ X, int node0, int m, int q8, float4 r[8]) {
    const float* xp = X + (size_t)(node0 + m) * F + q8;
#pragma unroll
    for (int kc = 0; kc < 4; ++kc) {
        r[2 * kc]     = *reinterpret_cast<const float4*>(xp + kc * 32);
        r[2 * kc + 1] = *reinterpret_cast<const float4*>(xp + kc * 32 + 4);
    }
}

__device__ __forceinline__
void splitA(const float4 r[8], bf16x8 Ahi[4], bf16x8 Alo[4]) {
#pragma unroll
    for (int kc = 0; kc < 4; ++kc) {
        float xv[8] = {r[2 * kc].x, r[2 * kc].y, r[2 * kc].z, r[2 * kc].w,
                       r[2 * kc + 1].x, r[2 * kc + 1].y, r[2 * kc + 1].z, r[2 * kc + 1].w};
#pragma unroll
        for (int t2 = 0; t2 < 8; ++t2) {
            short hh = f2bf(xv[t2]);
            Ahi[kc][t2] = hh;
            Alo[kc][t2] = f2bf(xv[t2] - bf2f(hh));
        }
    }
}

// MFMA chain + epilogue for one 16-row tile; HXB tile -> LDS (row stride HXP).
__device__ __forceinline__
void mfma_epi(int tile, const bf16x8 Ahi[4], const bf16x8 Alo[4],
              const bf16x8 Bhi[2][4], const bf16x8 Blo[2][4],
              float alw0, float alw16, float arw0, float arw16,
              short* hxs, float* __restrict__ AL,
              float* __restrict__ AR, int wave, int m, int q) {
    const int node0 = tile * 16;
    f32x4 acc0 = {0.f, 0.f, 0.f, 0.f};
    f32x4 acc1 = {0.f, 0.f, 0.f, 0.f};
#pragma unroll
    for (int kc = 0; kc < 4; ++kc) {
        acc0 = __builtin_amdgcn_mfma_f32_16x16x32_bf16(Ahi[kc], Bhi[0][kc], acc0, 0, 0, 0);
        acc1 = __builtin_amdgcn_mfma_f32_16x16x32_bf16(Ahi[kc], Bhi[1][kc], acc1, 0, 0, 0);
        acc0 = __builtin_amdgcn_mfma_f32_16x16x32_bf16(Ahi[kc], Blo[0][kc], acc0, 0, 0, 0);
        acc1 = __builtin_amdgcn_mfma_f32_16x16x32_bf16(Ahi[kc], Blo[1][kc], acc1, 0, 0, 0);
        acc0 = __builtin_amdgcn_mfma_f32_16x16x32_bf16(Alo[kc], Bhi[0][kc], acc0, 0, 0, 0);
        acc1 = __builtin_amdgcn_mfma_f32_16x16x32_bf16(Alo[kc], Bhi[1][kc], acc1, 0, 0, 0);
    }
    const int row0 = node0 + q * 4;
    const int col0 = wave * 32 + m;
#pragma unroll
    for (int r = 0; r < 4; ++r) {
        hxs[(q * 4 + r) * HXP + col0]      = f2bf(acc0[r]);
        hxs[(q * 4 + r) * HXP + col0 + 16] = f2bf(acc1[r]);
        float pal = acc0[r] * alw0 + acc1[r] * alw16;
        float par = acc0[r] * arw0 + acc1[r] * arw16;
#pragma unroll
        for (int o = 1; o < 16; o <<= 1) {
            pal += __shfl_xor(pal, o);
            par += __shfl_xor(par, o);
        }
        if (m == 0) {
            AL[(size_t)(row0 + r) * H + wave] = pal;
            AR[(size_t)(row0 + r) * H + wave] = par;
        }
    }
}

// Coalesced tile writeout: thread t stores one dwordx4; 16 lanes per row.
__device__ __forceinline__
void hxb_writeout(const short* hxs, int tile, __hip_bfloat16* __restrict__ HXB) {
    const int tid = threadIdx.x;
    const int row = tid >> 4;
    const int col = (tid & 15) * 8;
    uint4 v = *reinterpret_cast<const uint4*>(hxs + row * HXP + col);
    *reinterpret_cast<uint4*>(reinterpret_cast<short*>(HXB) +
                              (size_t)(tile * 16 + row) * F + col) = v;
}

// Two-tile gemm0 body, fp32 A and fp32 W0 (in-block split prologue,
// amortized over 2 tiles); prefetch tile-1 raw A before tile-0 compute.
__device__ __forceinline__
void gemm_pair_f32(int bid, const float* __restrict__ X,
                   const float* __restrict__ W0,
                   const float* __restrict__ attl, const float* __restrict__ attr,
                   __hip_bfloat16* __restrict__ HXB, float* __restrict__ AL,
                   float* __restrict__ AR, int ntiles, short* hxs) {
    const int wave = threadIdx.x >> 6;
    const int lane = threadIdx.x & 63;
    const int m    = lane & 15;
    const int q    = lane >> 4;
    const int q8   = q * 8;
    const int t0 = bid, t1 = bid + GB;
    const bool has1 = t1 < ntiles;
    float4 r0[8], r1[8];
    loadA_f32(X, t0 * 16, m, q8, r0);                 // issue A loads first
    if (has1) loadA_f32(X, t1 * 16, m, q8, r1);       // prefetch
    bf16x8 Bhi[2][4], Blo[2][4];
    bsetup_fp32(W0, wave, m, q8, Bhi, Blo);           // W-split hides under A loads
    const float alw0  = attl[wave * 32 + m];
    const float alw16 = attl[wave * 32 + 16 + m];
    const float arw0  = attr[wave * 32 + m];
    const float arw16 = attr[wave * 32 + 16 + m];
    bf16x8 Ahi[4], Alo[4];
    splitA(r0, Ahi, Alo);
    mfma_epi(t0, Ahi, Alo, Bhi, Blo, alw0, alw16, arw0, arw16, hxs, AL, AR, wave, m, q);
    if (has1) {
        splitA(r1, Ahi, Alo);
        mfma_epi(t1, Ahi, Alo, Bhi, Blo, alw0, alw16, arw0, arw16,
                 hxs + 16 * HXP, AL, AR, wave, m, q);
    }
    __syncthreads();
    hxb_writeout(hxs, t0, HXB);
    if (has1) hxb_writeout(hxs + 16 * HXP, t1, HXB);
}

// ===========================================================================
// k_mid: direct-scan bucket build [0,NBUCK) || W1-split [NBUCK,NBUCK+4) ||
// gemm0 [NBUCK+4, ...). ALL pieces depend only on kernel inputs -> this is
// the first dispatch (k_init eliminated).
// ===========================================================================
__global__ __launch_bounds__(256)
void k_mid(const int* __restrict__ ei, int E, int* __restrict__ deg,
           unsigned short* __restrict__ ssrc2u, int N,
           const float* __restrict__ X, const float* __restrict__ W0,
           const float* __restrict__ attl0, const float* __restrict__ attr0,
           __hip_bfloat16* __restrict__ HXB, float* __restrict__ AL,
           float* __restrict__ AR, int ntiles,
           const float* __restrict__ W1, short* __restrict__ W1hi,
           short* __restrict__ W1lo) {
    __shared__ union {
        struct {
            int cnt[BUCKW];
            unsigned short slots[BUCKW * MAXDEG];
        } bb;                                 // 25872 B
        short hxs[2 * 16 * HXP];              //  8704 B
    } sm;
    const int bid = blockIdx.x;
    if (bid < NBUCK)
        bucket_scan_body(bid, ei, E, deg, ssrc2u, N, sm.bb.cnt, sm.bb.slots);
    else if (bid < NBUCK + 4)
        wconv_part(bid - NBUCK, W1, W1hi, W1lo);
    else
        gemm_pair_f32(bid - NBUCK - 4, X, W0, attl0, attr0, HXB, AL, AR,
                      ntiles, sm.hxs);
}

// ===========================================================================
// Half-wave aggregation helpers (32 lanes/node, 4 features/lane).
// ===========================================================================
__device__ __forceinline__
int stage_node32(int g2, int lt, int n, const unsigned short* __restrict__ ssrc2u,
                 const int* __restrict__ deg, const float* __restrict__ AL,
                 const float4 ar4, int (*sidx)[MAXDEG], float (*sw)[MAXDEG][H]) {
    const int cnt  = min(deg[n], MAXDEG);
    const int rcnt = (cnt + PF - 1) & ~(PF - 1);
    for (int t2 = lt; t2 < rcnt; t2 += 32) {
        if (t2 < cnt) {
            int s = ssrc2u[(size_t)n * MAXDEG + t2];
            sidx[g2][t2] = s;
            float4 al4 = *reinterpret_cast<const float4*>(AL + (size_t)s * H);
            float a0 = al4.x + ar4.x; a0 = a0 > 0.f ? a0 : 0.2f * a0;
            float a1 = al4.y + ar4.y; a1 = a1 > 0.f ? a1 : 0.2f * a1;
            float a2 = al4.z + ar4.z; a2 = a2 > 0.f ? a2 : 0.2f * a2;
            float a3 = al4.w + ar4.w; a3 = a3 > 0.f ? a3 : 0.2f * a3;
            sw[g2][t2][0] = __expf(a0);
            sw[g2][t2][1] = __expf(a1);
            sw[g2][t2][2] = __expf(a2);
            sw[g2][t2][3] = __expf(a3);
        } else {
            sidx[g2][t2] = 0;
            sw[g2][t2][0] = 0.f; sw[g2][t2][1] = 0.f;
            sw[g2][t2][2] = 0.f; sw[g2][t2][3] = 0.f;
        }
    }
    __builtin_amdgcn_wave_barrier();
    return rcnt;
}

__device__ __forceinline__
void gather32(int g2, int lt, int rcnt, const __hip_bfloat16* __restrict__ HXB,
              const int (*sidx)[MAXDEG], const float (*sw)[MAXDEG][H],
              float& a0, float& a1, float& a2, float& a3, float& wsum) {
    const int h = lt >> 3;
    const unsigned short* hx = reinterpret_cast<const unsigned short*>(HXB);
    for (int base = 0; base < rcnt; base += PF) {
        ushort4 v[PF];
#pragma unroll
        for (int j = 0; j < PF; ++j) {
            int s = sidx[g2][base + j];
            v[j] = *reinterpret_cast<const ushort4*>(hx + (size_t)s * F + 4 * lt);
        }
#pragma unroll
        for (int j = 0; j < PF; ++j) {
            float w = sw[g2][base + j][h];
            a0 += w * bf2f((short)v[j].x);
            a1 += w * bf2f((short)v[j].y);
            a2 += w * bf2f((short)v[j].z);
            a3 += w * bf2f((short)v[j].w);
            wsum += w;
        }
    }
}

// ===========================================================================
// k_ag1: FUSED layer-0 aggregation + layer-1 GEMM, one 16-node tile per block.
// Phase 1 (2 rounds x 8 half-wave groups): gather + relu + split-bf16 X1 rows
// written to LDS ONLY. Phase 2: MFMA tile with A from LDS. Layer-1 outputs go
// to SEPARATE buffers (HXB1/AL1/AR1).
// ===========================================================================
__global__ __launch_bounds__(256)
void k_ag1(const unsigned short* __restrict__ ssrc2u, const int* __restrict__ deg,
           const float* __restrict__ AL0, const float* __restrict__ AR0,
           const __hip_bfloat16* __restrict__ HXB0, const float* __restrict__ b0,
           const short* __restrict__ W1hi, const short* __restrict__ W1lo,
           const float* __restrict__ attl1, const float* __restrict__ attr1,
           __hip_bfloat16* __restrict__ HXB1, float* __restrict__ AL1,
           float* __restrict__ AR1, int ntiles) {
    __shared__ int   sidx[8][MAXDEG];
    __shared__ float sw[8][MAXDEG][H];      // 16 KB; reused as hxs after barrier
    __shared__ short x1h[16 * HXP];
    __shared__ short x1l[16 * HXP];
    const int tid  = threadIdx.x;
    const int g2   = tid >> 5;
    const int lt   = tid & 31;
    const int tile = blockIdx.x;

    // ---- phase 1: aggregate 16 nodes (2 rounds of 8), X1 -> LDS ----------
#pragma unroll
    for (int r = 0; r < 2; ++r) {
        const int n = tile * 16 + r * 8 + g2;
        const float4 ar4 = *reinterpret_cast<const float4*>(AR0 + (size_t)n * H);
        int rcnt = stage_node32(g2, lt, n, ssrc2u, deg, AL0, ar4, sidx, sw);
        float a0 = 0.f, a1 = 0.f, a2 = 0.f, a3 = 0.f, ws = 0.f;
        gather32(g2, lt, rcnt, HXB0, sidx, sw, a0, a1, a2, a3, ws);
        float inv = 1.f / (ws + 1e-9f);
        const float4 b4 = *reinterpret_cast<const float4*>(b0 + 4 * lt);
        float o0 = fmaxf(a0 * inv + b4.x, 0.f);
        float o1 = fmaxf(a1 * inv + b4.y, 0.f);
        float o2 = fmaxf(a2 * inv + b4.z, 0.f);
        float o3 = fmaxf(a3 * inv + b4.w, 0.f);
        short h0 = f2bf(o0), h1 = f2bf(o1), h2 = f2bf(o2), h3 = f2bf(o3);
        short l0 = f2bf(o0 - bf2f(h0)), l1 = f2bf(o1 - bf2f(h1));
        short l2 = f2bf(o2 - bf2f(h2)), l3 = f2bf(o3 - bf2f(h3));
        const int row = r * 8 + g2;
        uint2 hw, lw;
        hw.x = (unsigned)(unsigned short)h0 | ((unsigned)(unsigned short)h1 << 16);
        hw.y = (unsigned)(unsigned short)h2 | ((unsigned)(unsigned short)h3 << 16);
        lw.x = (unsigned)(unsigned short)l0 | ((unsigned)(unsigned short)l1 << 16);
        lw.y = (unsigned)(unsigned short)l2 | ((unsigned)(unsigned short)l3 << 16);
        *reinterpret_cast<uint2*>(x1h + row * HXP + 4 * lt) = hw;
        *reinterpret_cast<uint2*>(x1l + row * HXP + 4 * lt) = lw;
    }
    __syncthreads();   // X1 tile complete in LDS; sw dead from here

    // ---- phase 2: layer-1 GEMM tile, A from LDS ---------------------------
    short* hxs = reinterpret_cast<short*>(sw);   // reuse (safe post-barrier)
    {
        const int wave = tid >> 6;
        const int lane = tid & 63;
        const int m    = lane & 15;
        const int q    = lane >> 4;
        const int q8   = q * 8;
        bf16x8 Bhi[2][4], Blo[2][4];
        bsetup_pre(W1hi, W1lo, wave, m, q8, Bhi, Blo);
        const float alw0  = attl1[wave * 32 + m];
        const float alw16 = attl1[wave * 32 + 16 + m];
        const float arw0  = attr1[wave * 32 + m];
        const float arw16 = attr1[wave * 32 + 16 + m];
        bf16x8 Ahi[4], Alo[4];
#pragma unroll
        for (int kc = 0; kc < 4; ++kc) {
            Ahi[kc] = *reinterpret_cast<const bf16x8*>(x1h + m * HXP + kc * 32 + q8);
            Alo[kc] = *reinterpret_cast<const bf16x8*>(x1l + m * HXP + kc * 32 + q8);
        }
        mfma_epi(tile, Ahi, Alo, Bhi, Blo, alw0, alw16, arw0, arw16,
                 hxs, AL1, AR1, wave, m, q);
    }
    __syncthreads();
    hxb_writeout(hxs, tile, HXB1);
}

// k_aggr1: layer-1 aggregation + head-mean (half-wave), reads HXB1/AL1/AR1.
__global__ __launch_bounds__(256)
void k_aggr1(const unsigned short* __restrict__ ssrc2u, const int* __restrict__ deg,
             const float* __restrict__ AL, const float* __restrict__ AR,
             const __hip_bfloat16* __restrict__ HXB, const float* __restrict__ bias,
             float* __restrict__ out, int N) {
    __shared__ int   sidx[8][MAXDEG];
    __shared__ float sw[8][MAXDEG][H];
    const int tid = threadIdx.x;
    const int g2  = tid >> 5;
    const int lt  = tid & 31;
    const int n   = blockIdx.x * 8 + g2;
    const float4 ar4 = *reinterpret_cast<const float4*>(AR + (size_t)n * H);
    int rcnt = stage_node32(g2, lt, n, ssrc2u, deg, AL, ar4, sidx, sw);
    float a0 = 0.f, a1 = 0.f, a2 = 0.f, a3 = 0.f, ws = 0.f;
    gather32(g2, lt, rcnt, HXB, sidx, sw, a0, a1, a2, a3, ws);
    float inv = 1.f / (ws + 1e-9f);
    float v0 = a0 * inv, v1 = a1 * inv, v2 = a2 * inv, v3 = a3 * inv;
    v0 += __shfl_xor(v0, 8);  v1 += __shfl_xor(v1, 8);
    v2 += __shfl_xor(v2, 8);  v3 += __shfl_xor(v3, 8);
    v0 += __shfl_xor(v0, 16); v1 += __shfl_xor(v1, 16);
    v2 += __shfl_xor(v2, 16); v3 += __shfl_xor(v3, 16);
    if (lt < 8) {
        const float4 b4 = *reinterpret_cast<const float4*>(bias + 4 * lt);
        float4 o;
        o.x = 0.25f * v0 + b4.x;
        o.y = 0.25f * v1 + b4.y;
        o.z = 0.25f * v2 + b4.z;
        o.w = 0.25f * v3 + b4.w;
        *reinterpret_cast<float4*>(out + (size_t)n * D + 4 * lt) = o;
    }
}

// ===========================================================================
extern "C" void kernel_launch(void* const* d_in, const int* in_sizes, int n_in,
                              void* d_out, int out_size, void* d_ws, size_t ws_size,
                              hipStream_t stream) {
    const float* x     = (const float*)d_in[0];
    const int*   ei    = (const int*)d_in[1];
    const float* W0    = (const float*)d_in[2];
    const float* attl0 = (const float*)d_in[3];
    const float* attr0 = (const float*)d_in[4];
    const float* b0    = (const float*)d_in[5];
    const float* W1    = (const float*)d_in[6];
    const float* attl1 = (const float*)d_in[7];
    const float* attr1 = (const float*)d_in[8];
    const float* b1    = (const float*)d_in[9];

    const int N = in_sizes[0] / F;   // 50000
    const int E = in_sizes[1] / 2;   // 800000
    const int ntiles = N / 16;       // 3125

    // Workspace: HXB0 | HXB1 | W1hi | W1lo | AL0 | AR0 | AL1 | AR1 |
    //            ssrc2u (PADDED NBUCK*BUCKW nodes) | deg
    char* p = (char*)d_ws;
    __hip_bfloat16* HXB0 = (__hip_bfloat16*)p; p += (size_t)N * F * 2;
    __hip_bfloat16* HXB1 = (__hip_bfloat16*)p; p += (size_t)N * F * 2;
    short* W1hi = (short*)p;                   p += (size_t)F * F * 2;
    short* W1lo = (short*)p;                   p += (size_t)F * F * 2;
    float* AL0  = (float*)p;                   p += (size_t)N * H * 4;
    float* AR0  = (float*)p;                   p += (size_t)N * H * 4;
    float* AL1  = (float*)p;                   p += (size_t)N * H * 4;
    float* AR1  = (float*)p;                   p += (size_t)N * H * 4;
    unsigned short* ssrc2u = (unsigned short*)p;
    p += (size_t)NBUCK * BUCKW * MAXDEG * 2;   // padded: bucket writeout covers 50176 nodes
    int* deg = (int*)p;

    // k_mid: direct-scan bucket build || W1-split || gemm0 (one dispatch,
    // everything input-dependent only — k_init eliminated)
    k_mid<<<NBUCK + 4 + GB, 256, 0, stream>>>(ei, E, deg, ssrc2u, N,
                                              x, W0, attl0, attr0,
                                              HXB0, AL0, AR0, ntiles,
                                              W1, W1hi, W1lo);

    // k_ag1: FUSED layer-0 aggregation + layer-1 GEMM (X1 never hits global)
    k_ag1<<<ntiles, 256, 0, stream>>>(ssrc2u, deg, AL0, AR0, HXB0, b0,
                                      W1hi, W1lo, attl1, attr1,
                                      HXB1, AL1, AR1, ntiles);

    // layer-1 aggregation + head-mean (half-wave)
    k_aggr1<<<N / 8, 256, 0, stream>>>(ssrc2u, deg, AL1, AR1, HXB1, b1,
                                       (float*)d_out, N);
}

// Round 11
// 210.389 us; speedup vs baseline: 2.4729x; 2.4729x over previous
//
#include <hip/hip_runtime.h>
#include <hip/hip_bf16.h>

#define H 4
#define D 32
#define F 128      // H*D
#define MAXDEG 64  // slot capacity per dst (Poisson(16), max ~45)
#define PF 8       // gather prefetch depth (16-B rows in flight per lane)
#define NBUCK 256  // dst-range buckets for the 2-phase adjacency build
#define BUCKW 196  // dst range width per bucket (256*196 = 50176 >= N)
#define NABLK 128  // bucket phase-A blocks (E/128 = 6250 edges each)
#define SEGCAP 64  // per-(block,bucket) segment capacity (Binom mean 24.4 + 8 sigma)
#define GB    1563 // gemm blocks: 2 tiles/block over 3125 tiles
#define HXP   136  // LDS row stride (shorts), 16B-aligned rows

typedef __attribute__((ext_vector_type(8))) short bf16x8;  // 8 bf16 (4 VGPRs)
typedef __attribute__((ext_vector_type(4))) float f32x4;

__device__ __forceinline__ short f2bf(float v) {
    __hip_bfloat16 h = __float2bfloat16(v);   // RNE
    return *reinterpret_cast<short*>(&h);
}
__device__ __forceinline__ float bf2f(short s) {
    __hip_bfloat16 h = *reinterpret_cast<__hip_bfloat16*>(&s);
    return __bfloat162float(h);
}

// ===========================================================================
// W split piece (fp32 -> bf16 hi/lo), one part = 1/4 of one matrix.
// ===========================================================================
__device__ __forceinline__
void wconv_part(int part8, const float* __restrict__ W0, short* __restrict__ W0hi,
                short* __restrict__ W0lo, const float* __restrict__ W1,
                short* __restrict__ W1hi, short* __restrict__ W1lo) {
    const int tid = threadIdx.x;
    const float* W  = (part8 < 4) ? W0 : W1;
    short* Whi = (part8 < 4) ? W0hi : W1hi;
    short* Wlo = (part8 < 4) ? W0lo : W1lo;
    const int part = part8 & 3;
    const int base = part * (F * F / 4);     // 4096 elems per part
    for (int i = base + tid * 4; i < base + F * F / 4; i += 1024) {
        float4 v = *reinterpret_cast<const float4*>(W + i);
        float vv[4] = {v.x, v.y, v.z, v.w};
        short hs[4], ls[4];
#pragma unroll
        for (int j = 0; j < 4; ++j) {
            hs[j] = f2bf(vv[j]);
            ls[j] = f2bf(vv[j] - bf2f(hs[j]));
        }
        *reinterpret_cast<short4*>(Whi + i) = make_short4(hs[0], hs[1], hs[2], hs[3]);
        *reinterpret_cast<short4*>(Wlo + i) = make_short4(ls[0], ls[1], ls[2], ls[3]);
    }
}

// ===========================================================================
// Bucket-sort phase A, ATOMIC-FREE in global memory (round-5 design; the
// round-10 direct-scan alternative was 40x slower — 781-iter serial L3 scan).
// ===========================================================================
__device__ __forceinline__
void bucketA_body(int abid, const int* __restrict__ ei, int E,
                  int* __restrict__ cntmat, unsigned int* __restrict__ buf) {
    __shared__ int lcnt[NBUCK];
    const int tid = threadIdx.x;
    lcnt[tid] = 0;
    __syncthreads();
    const int per = ((E / NABLK) + 3) & ~3;      // 6252 (mult of 4)
    const int e0 = abid * per;
    const int e1 = min(e0 + per, E);
    for (int e = e0 + 4 * tid; e < e1; e += 1024) {
        int4 dv = *reinterpret_cast<const int4*>(ei + E + e);
        atomicAdd(&lcnt[dv.x / BUCKW], 1);
        atomicAdd(&lcnt[dv.y / BUCKW], 1);
        atomicAdd(&lcnt[dv.z / BUCKW], 1);
        atomicAdd(&lcnt[dv.w / BUCKW], 1);
    }
    __syncthreads();
    cntmat[abid * NBUCK + tid] = min(lcnt[tid], SEGCAP);
    lcnt[tid] = 0;
    __syncthreads();
    for (int e = e0 + 4 * tid; e < e1; e += 1024) {
        int4 sv = *reinterpret_cast<const int4*>(ei + e);
        int4 dv = *reinterpret_cast<const int4*>(ei + E + e);
        int ss[4] = {sv.x, sv.y, sv.z, sv.w};
        int dd[4] = {dv.x, dv.y, dv.z, dv.w};
#pragma unroll
        for (int j = 0; j < 4; ++j) {
            int b = dd[j] / BUCKW;
            int pos = atomicAdd(&lcnt[b], 1);   // LDS atomic only
            if (pos < SEGCAP)
                buf[((size_t)b * NABLK + abid) * SEGCAP + pos] =
                    (unsigned)ss[j] | ((unsigned)(dd[j] - b * BUCKW) << 16);
        }
    }
}

// k_init: bucketA [0,NABLK) | W-splits [NABLK, NABLK+8).
__global__ __launch_bounds__(256)
void k_init(const int* __restrict__ ei, int E, int* __restrict__ cntmat,
            unsigned int* __restrict__ buf,
            const float* __restrict__ W0, short* __restrict__ W0hi,
            short* __restrict__ W0lo, const float* __restrict__ W1,
            short* __restrict__ W1hi, short* __restrict__ W1lo) {
    const int bid = blockIdx.x;
    if (bid < NABLK)
        bucketA_body(bid, ei, E, cntmat, buf);
    else
        wconv_part(bid - NABLK, W0, W0hi, W0lo, W1, W1hi, W1lo);
}

// ===========================================================================
// Bucket phase B (device body): LDS arrays passed in (union'd in k_mid).
// ===========================================================================
__device__ __forceinline__
void bucketB_body(int b, const unsigned int* __restrict__ buf,
                  const int* __restrict__ cntmat, int* __restrict__ deg,
                  unsigned short* __restrict__ ssrc2u, int N,
                  int* cnt, int* scnt, unsigned short* slots) {
    const int tid = threadIdx.x;
    if (tid < BUCKW) cnt[tid] = 0;
    if (tid < NABLK) scnt[tid] = cntmat[tid * NBUCK + b];
    __syncthreads();
    const int a    = tid & (NABLK - 1);
    const int half = tid >> 7;            // 0 or 1
    const int mm   = scnt[a];
    const unsigned int* seg = buf + ((size_t)b * NABLK + a) * SEGCAP;
    for (int c = half * 4; c < mm; c += 8) {
        uint4 r = *reinterpret_cast<const uint4*>(seg + c);
        unsigned rr[4] = {r.x, r.y, r.z, r.w};
#pragma unroll
        for (int j = 0; j < 4; ++j) {
            if (c + j < mm) {
                int src  = rr[j] & 0xffff;
                int ldst = rr[j] >> 16;
                int slot = atomicAdd(&cnt[ldst], 1);   // LDS atomic
                if (slot < MAXDEG)
                    slots[ldst * MAXDEG + slot] = (unsigned short)src;
            }
        }
    }
    __syncthreads();
    uint4* dst = reinterpret_cast<uint4*>(ssrc2u + (size_t)b * BUCKW * MAXDEG);
    const uint4* s4 = reinterpret_cast<const uint4*>(slots);
    for (int i = tid; i < BUCKW * MAXDEG / 8; i += 256)
        dst[i] = s4[i];
    if (tid < BUCKW) {
        int node = b * BUCKW + tid;
        if (node < N) deg[node] = cnt[tid];
    }
}

// ===========================================================================
// GEMM shared pieces. MFMA layouts (m89, proven in prior rounds):
// A[m=lane&15][k=q*8+j], B[n=lane&15][k=q*8+j], C col=lane&15, row=q*4+reg.
// ===========================================================================
__device__ __forceinline__
void bsetup_pre(const short* __restrict__ Whi, const short* __restrict__ Wlo,
                int wave, int m, int q8, bf16x8 Bhi[2][4], bf16x8 Blo[2][4]) {
#pragma unroll
    for (int j = 0; j < 2; ++j) {
        const int fout = wave * 32 + j * 16 + m;
#pragma unroll
        for (int kc = 0; kc < 4; ++kc) {
            Bhi[j][kc] = *reinterpret_cast<const bf16x8*>(Whi + (size_t)fout * F + kc * 32 + q8);
            Blo[j][kc] = *reinterpret_cast<const bf16x8*>(Wlo + (size_t)fout * F + kc * 32 + q8);
        }
    }
}

__device__ __forceinline__
void loadA_f32(const float* __restrict__ X, int node0, int m, int q8, float4 r[8]) {
    const float* xp = X + (size_t)(node0 + m) * F + q8;
#pragma unroll
    for (int kc = 0; kc < 4; ++kc) {
        r[2 * kc]     = *reinterpret_cast<const float4*>(xp + kc * 32);
        r[2 * kc + 1] = *reinterpret_cast<const float4*>(xp + kc * 32 + 4);
    }
}

__device__ __forceinline__
void splitA(const float4 r[8], bf16x8 Ahi[4], bf16x8 Alo[4]) {
#pragma unroll
    for (int kc = 0; kc < 4; ++kc) {
        float xv[8] = {r[2 * kc].x, r[2 * kc].y, r[2 * kc].z, r[2 * kc].w,
                       r[2 * kc + 1].x, r[2 * kc + 1].y, r[2 * kc + 1].z, r[2 * kc + 1].w};
#pragma unroll
        for (int t2 = 0; t2 < 8; ++t2) {
            short hh = f2bf(xv[t2]);
            Ahi[kc][t2] = hh;
            Alo[kc][t2] = f2bf(xv[t2] - bf2f(hh));
        }
    }
}

// MFMA chain + epilogue for one 16-row tile; HXB tile -> LDS (row stride HXP).
__device__ __forceinline__
void mfma_epi(int tile, const bf16x8 Ahi[4], const bf16x8 Alo[4],
              const bf16x8 Bhi[2][4], const bf16x8 Blo[2][4],
              float alw0, float alw16, float arw0, float arw16,
              short* hxs, float* __restrict__ AL,
              float* __restrict__ AR, int wave, int m, int q) {
    const int node0 = tile * 16;
    f32x4 acc0 = {0.f, 0.f, 0.f, 0.f};
    f32x4 acc1 = {0.f, 0.f, 0.f, 0.f};
#pragma unroll
    for (int kc = 0; kc < 4; ++kc) {
        acc0 = __builtin_amdgcn_mfma_f32_16x16x32_bf16(Ahi[kc], Bhi[0][kc], acc0, 0, 0, 0);
        acc1 = __builtin_amdgcn_mfma_f32_16x16x32_bf16(Ahi[kc], Bhi[1][kc], acc1, 0, 0, 0);
        acc0 = __builtin_amdgcn_mfma_f32_16x16x32_bf16(Ahi[kc], Blo[0][kc], acc0, 0, 0, 0);
        acc1 = __builtin_amdgcn_mfma_f32_16x16x32_bf16(Ahi[kc], Blo[1][kc], acc1, 0, 0, 0);
        acc0 = __builtin_amdgcn_mfma_f32_16x16x32_bf16(Alo[kc], Bhi[0][kc], acc0, 0, 0, 0);
        acc1 = __builtin_amdgcn_mfma_f32_16x16x32_bf16(Alo[kc], Bhi[1][kc], acc1, 0, 0, 0);
    }
    const int row0 = node0 + q * 4;
    const int col0 = wave * 32 + m;
#pragma unroll
    for (int r = 0; r < 4; ++r) {
        hxs[(q * 4 + r) * HXP + col0]      = f2bf(acc0[r]);
        hxs[(q * 4 + r) * HXP + col0 + 16] = f2bf(acc1[r]);
        float pal = acc0[r] * alw0 + acc1[r] * alw16;
        float par = acc0[r] * arw0 + acc1[r] * arw16;
#pragma unroll
        for (int o = 1; o < 16; o <<= 1) {
            pal += __shfl_xor(pal, o);
            par += __shfl_xor(par, o);
        }
        if (m == 0) {
            AL[(size_t)(row0 + r) * H + wave] = pal;
            AR[(size_t)(row0 + r) * H + wave] = par;
        }
    }
}

// Coalesced tile writeout: thread t stores one dwordx4; 16 lanes per row.
__device__ __forceinline__
void hxb_writeout(const short* hxs, int tile, __hip_bfloat16* __restrict__ HXB) {
    const int tid = threadIdx.x;
    const int row = tid >> 4;
    const int col = (tid & 15) * 8;
    uint4 v = *reinterpret_cast<const uint4*>(hxs + row * HXP + col);
    *reinterpret_cast<uint4*>(reinterpret_cast<short*>(HXB) +
                              (size_t)(tile * 16 + row) * F + col) = v;
}

// Two-tile gemm0 body, fp32 A, pre-split W0.
__device__ __forceinline__
void gemm_pair_f32(int bid, const float* __restrict__ X,
                   const short* __restrict__ Whi, const short* __restrict__ Wlo,
                   const float* __restrict__ attl, const float* __restrict__ attr,
                   __hip_bfloat16* __restrict__ HXB, float* __restrict__ AL,
                   float* __restrict__ AR, int ntiles, short* hxs) {
    const int wave = threadIdx.x >> 6;
    const int lane = threadIdx.x & 63;
    const int m    = lane & 15;
    const int q    = lane >> 4;
    const int q8   = q * 8;
    bf16x8 Bhi[2][4], Blo[2][4];
    bsetup_pre(Whi, Wlo, wave, m, q8, Bhi, Blo);
    const float alw0  = attl[wave * 32 + m];
    const float alw16 = attl[wave * 32 + 16 + m];
    const float arw0  = attr[wave * 32 + m];
    const float arw16 = attr[wave * 32 + 16 + m];

    const int t0 = bid, t1 = bid + GB;
    const bool has1 = t1 < ntiles;
    float4 r0[8], r1[8];
    loadA_f32(X, t0 * 16, m, q8, r0);
    if (has1) loadA_f32(X, t1 * 16, m, q8, r1);   // prefetch
    bf16x8 Ahi[4], Alo[4];
    splitA(r0, Ahi, Alo);
    mfma_epi(t0, Ahi, Alo, Bhi, Blo, alw0, alw16, arw0, arw16, hxs, AL, AR, wave, m, q);
    if (has1) {
        splitA(r1, Ahi, Alo);
        mfma_epi(t1, Ahi, Alo, Bhi, Blo, alw0, alw16, arw0, arw16,
                 hxs + 16 * HXP, AL, AR, wave, m, q);
    }
    __syncthreads();
    hxb_writeout(hxs, t0, HXB);
    if (has1) hxb_writeout(hxs + 16 * HXP, t1, HXB);
}

// k_mid: bucketB [0,NBUCK) runs concurrently with gemm0 [NBUCK, NBUCK+GB).
__global__ __launch_bounds__(256)
void k_mid(const unsigned int* __restrict__ buf, const int* __restrict__ cntmat,
           int* __restrict__ deg, unsigned short* __restrict__ ssrc2u, int N,
           const float* __restrict__ X, const short* __restrict__ W0hi,
           const short* __restrict__ W0lo, const float* __restrict__ attl0,
           const float* __restrict__ attr0, __hip_bfloat16* __restrict__ HXB,
           float* __restrict__ AL, float* __restrict__ AR, int ntiles) {
    __shared__ union {
        struct {
            int cnt[BUCKW];
            int scnt[NABLK];
            unsigned short slots[BUCKW * MAXDEG];
        } bb;                                 // 26384 B
        short hxs[2 * 16 * HXP];              //  8704 B
    } sm;
    const int bid = blockIdx.x;
    if (bid < NBUCK)
        bucketB_body(bid, buf, cntmat, deg, ssrc2u, N,
                     sm.bb.cnt, sm.bb.scnt, sm.bb.slots);
    else
        gemm_pair_f32(bid - NBUCK, X, W0hi, W0lo, attl0, attr0, HXB, AL, AR,
                      ntiles, sm.hxs);
}

// ===========================================================================
// 16-lane-group aggregation: lane lt covers features [8lt, 8lt+7] (one 16-B
// load per edge-row). 16 nodes per 256-thr block in ONE round (vs round-9's
// 2 serial rounds of 8): halves per-block serial depth, doubles node
// concurrency; in-flight bytes unchanged (PF 16x8B -> 8x16B). Bit-exact:
// same per-feature accumulation order, zero-weight dummies, head grouping.
// ===========================================================================
__device__ __forceinline__
int stage_node16(int g, int lt, int n, const unsigned short* __restrict__ ssrc2u,
                 const int* __restrict__ deg, const float* __restrict__ AL,
                 const float4 ar4, int (*sidx)[MAXDEG], float (*sw)[MAXDEG][H]) {
    const int cnt  = min(deg[n], MAXDEG);
    const int rcnt = (cnt + PF - 1) & ~(PF - 1);
    for (int t2 = lt; t2 < rcnt; t2 += 16) {
        if (t2 < cnt) {
            int s = ssrc2u[(size_t)n * MAXDEG + t2];
            sidx[g][t2] = s;
            float4 al4 = *reinterpret_cast<const float4*>(AL + (size_t)s * H);
            float a0 = al4.x + ar4.x; a0 = a0 > 0.f ? a0 : 0.2f * a0;
            float a1 = al4.y + ar4.y; a1 = a1 > 0.f ? a1 : 0.2f * a1;
            float a2 = al4.z + ar4.z; a2 = a2 > 0.f ? a2 : 0.2f * a2;
            float a3 = al4.w + ar4.w; a3 = a3 > 0.f ? a3 : 0.2f * a3;
            sw[g][t2][0] = __expf(a0);
            sw[g][t2][1] = __expf(a1);
            sw[g][t2][2] = __expf(a2);
            sw[g][t2][3] = __expf(a3);
        } else {
            sidx[g][t2] = 0;
            sw[g][t2][0] = 0.f; sw[g][t2][1] = 0.f;
            sw[g][t2][2] = 0.f; sw[g][t2][3] = 0.f;
        }
    }
    __builtin_amdgcn_wave_barrier();
    return rcnt;
}

__device__ __forceinline__
void gather16(int g, int lt, int rcnt, const __hip_bfloat16* __restrict__ HXB,
              const int (*sidx)[MAXDEG], const float (*sw)[MAXDEG][H],
              float a[8], float& wsum) {
    const int h = lt >> 2;
    const unsigned short* hx = reinterpret_cast<const unsigned short*>(HXB);
    for (int base = 0; base < rcnt; base += PF) {
        uint4 v[PF];
#pragma unroll
        for (int j = 0; j < PF; ++j) {
            int s = sidx[g][base + j];
            v[j] = *reinterpret_cast<const uint4*>(hx + (size_t)s * F + 8 * lt);
        }
#pragma unroll
        for (int j = 0; j < PF; ++j) {
            float w = sw[g][base + j][h];
            unsigned ww[4] = {v[j].x, v[j].y, v[j].z, v[j].w};
#pragma unroll
            for (int k = 0; k < 4; ++k) {
                a[2 * k]     += w * bf2f((short)(ww[k] & 0xffff));
                a[2 * k + 1] += w * bf2f((short)(ww[k] >> 16));
            }
            wsum += w;
        }
    }
}

// ===========================================================================
// k_ag1: FUSED layer-0 aggregation + layer-1 GEMM, one 16-node tile per block.
// Phase 1 (ONE round, 16 16-lane groups): gather + relu + split-bf16 X1 rows
// to LDS ONLY. Phase 2: MFMA tile with A from LDS -> HXB1/AL1/AR1.
// ===========================================================================
__global__ __launch_bounds__(256)
void k_ag1(const unsigned short* __restrict__ ssrc2u, const int* __restrict__ deg,
           const float* __restrict__ AL0, const float* __restrict__ AR0,
           const __hip_bfloat16* __restrict__ HXB0, const float* __restrict__ b0,
           const short* __restrict__ W1hi, const short* __restrict__ W1lo,
           const float* __restrict__ attl1, const float* __restrict__ attr1,
           __hip_bfloat16* __restrict__ HXB1, float* __restrict__ AL1,
           float* __restrict__ AR1, int ntiles) {
    __shared__ int   sidx[16][MAXDEG];      // 4 KB
    __shared__ float sw[16][MAXDEG][H];     // 16 KB; reused as hxs after barrier
    __shared__ short x1h[16 * HXP];
    __shared__ short x1l[16 * HXP];
    const int tid  = threadIdx.x;
    const int g    = tid >> 4;
    const int lt   = tid & 15;
    const int tile = blockIdx.x;

    // ---- phase 1: aggregate 16 nodes in one round, X1 -> LDS -------------
    {
        const int n = tile * 16 + g;
        const float4 ar4 = *reinterpret_cast<const float4*>(AR0 + (size_t)n * H);
        int rcnt = stage_node16(g, lt, n, ssrc2u, deg, AL0, ar4, sidx, sw);
        float a[8] = {0.f, 0.f, 0.f, 0.f, 0.f, 0.f, 0.f, 0.f};
        float ws = 0.f;
        gather16(g, lt, rcnt, HXB0, sidx, sw, a, ws);
        float inv = 1.f / (ws + 1e-9f);
        const float4 b4a = *reinterpret_cast<const float4*>(b0 + 8 * lt);
        const float4 b4b = *reinterpret_cast<const float4*>(b0 + 8 * lt + 4);
        float bb[8] = {b4a.x, b4a.y, b4a.z, b4a.w, b4b.x, b4b.y, b4b.z, b4b.w};
        unsigned hw[4], lw[4];
#pragma unroll
        for (int k = 0; k < 4; ++k) {
            float o0 = fmaxf(a[2 * k] * inv + bb[2 * k], 0.f);
            float o1 = fmaxf(a[2 * k + 1] * inv + bb[2 * k + 1], 0.f);
            short h0 = f2bf(o0), h1 = f2bf(o1);
            short l0 = f2bf(o0 - bf2f(h0)), l1 = f2bf(o1 - bf2f(h1));
            hw[k] = (unsigned)(unsigned short)h0 | ((unsigned)(unsigned short)h1 << 16);
            lw[k] = (unsigned)(unsigned short)l0 | ((unsigned)(unsigned short)l1 << 16);
        }
        uint4 hv = {hw[0], hw[1], hw[2], hw[3]};
        uint4 lv = {lw[0], lw[1], lw[2], lw[3]};
        *reinterpret_cast<uint4*>(x1h + g * HXP + 8 * lt) = hv;
        *reinterpret_cast<uint4*>(x1l + g * HXP + 8 * lt) = lv;
    }
    __syncthreads();   // X1 tile complete in LDS; sw dead from here

    // ---- phase 2: layer-1 GEMM tile, A from LDS ---------------------------
    short* hxs = reinterpret_cast<short*>(sw);   // reuse (safe post-barrier)
    {
        const int wave = tid >> 6;
        const int lane = tid & 63;
        const int m    = lane & 15;
        const int q    = lane >> 4;
        const int q8   = q * 8;
        bf16x8 Bhi[2][4], Blo[2][4];
        bsetup_pre(W1hi, W1lo, wave, m, q8, Bhi, Blo);
        const float alw0  = attl1[wave * 32 + m];
        const float alw16 = attl1[wave * 32 + 16 + m];
        const float arw0  = attr1[wave * 32 + m];
        const float arw16 = attr1[wave * 32 + 16 + m];
        bf16x8 Ahi[4], Alo[4];
#pragma unroll
        for (int kc = 0; kc < 4; ++kc) {
            Ahi[kc] = *reinterpret_cast<const bf16x8*>(x1h + m * HXP + kc * 32 + q8);
            Alo[kc] = *reinterpret_cast<const bf16x8*>(x1l + m * HXP + kc * 32 + q8);
        }
        mfma_epi(tile, Ahi, Alo, Bhi, Blo, alw0, alw16, arw0, arw16,
                 hxs, AL1, AR1, wave, m, q);
    }
    __syncthreads();
    hxb_writeout(hxs, tile, HXB1);
}

// k_aggr1: layer-1 aggregation + head-mean (16-lane groups, 16 nodes/block).
// Head grouping ((h0+h1)+(h2+h3)) via xor4 then xor8 — bit-exact vs round 9.
__global__ __launch_bounds__(256)
void k_aggr1(const unsigned short* __restrict__ ssrc2u, const int* __restrict__ deg,
             const float* __restrict__ AL, const float* __restrict__ AR,
             const __hip_bfloat16* __restrict__ HXB, const float* __restrict__ bias,
             float* __restrict__ out, int N) {
    __shared__ int   sidx[16][MAXDEG];
    __shared__ float sw[16][MAXDEG][H];
    const int tid = threadIdx.x;
    const int g   = tid >> 4;
    const int lt  = tid & 15;
    const int n   = blockIdx.x * 16 + g;   // N = 50000 = 3125*16, no tail
    const float4 ar4 = *reinterpret_cast<const float4*>(AR + (size_t)n * H);
    int rcnt = stage_node16(g, lt, n, ssrc2u, deg, AL, ar4, sidx, sw);
    float a[8] = {0.f, 0.f, 0.f, 0.f, 0.f, 0.f, 0.f, 0.f};
    float ws = 0.f;
    gather16(g, lt, rcnt, HXB, sidx, sw, a, ws);
    float inv = 1.f / (ws + 1e-9f);
    float v[8];
#pragma unroll
    for (int k = 0; k < 8; ++k) {
        v[k] = a[k] * inv;
        v[k] += __shfl_xor(v[k], 4);    // h0+h1, h2+h3
        v[k] += __shfl_xor(v[k], 8);    // (h0+h1)+(h2+h3)
    }
    if (lt < 4) {
        const float4 b4a = *reinterpret_cast<const float4*>(bias + 8 * lt);
        const float4 b4b = *reinterpret_cast<const float4*>(bias + 8 * lt + 4);
        float4 o0, o1;
        o0.x = 0.25f * v[0] + b4a.x;
        o0.y = 0.25f * v[1] + b4a.y;
        o0.z = 0.25f * v[2] + b4a.z;
        o0.w = 0.25f * v[3] + b4a.w;
        o1.x = 0.25f * v[4] + b4b.x;
        o1.y = 0.25f * v[5] + b4b.y;
        o1.z = 0.25f * v[6] + b4b.z;
        o1.w = 0.25f * v[7] + b4b.w;
        *reinterpret_cast<float4*>(out + (size_t)n * D + 8 * lt)     = o0;
        *reinterpret_cast<float4*>(out + (size_t)n * D + 8 * lt + 4) = o1;
    }
}

// ===========================================================================
extern "C" void kernel_launch(void* const* d_in, const int* in_sizes, int n_in,
                              void* d_out, int out_size, void* d_ws, size_t ws_size,
                              hipStream_t stream) {
    const float* x     = (const float*)d_in[0];
    const int*   ei    = (const int*)d_in[1];
    const float* W0    = (const float*)d_in[2];
    const float* attl0 = (const float*)d_in[3];
    const float* attr0 = (const float*)d_in[4];
    const float* b0    = (const float*)d_in[5];
    const float* W1    = (const float*)d_in[6];
    const float* attl1 = (const float*)d_in[7];
    const float* attr1 = (const float*)d_in[8];
    const float* b1    = (const float*)d_in[9];

    const int N = in_sizes[0] / F;   // 50000
    const int E = in_sizes[1] / 2;   // 800000
    const int ntiles = N / 16;       // 3125

    // Workspace: HXB0 | HXB1 | W0hi | W0lo | W1hi | W1lo | AL0 | AR0 |
    //            AL1 | AR1 | ssrc2u (PADDED NBUCK*BUCKW nodes) | deg | buf | cntmat
    char* p = (char*)d_ws;
    __hip_bfloat16* HXB0 = (__hip_bfloat16*)p; p += (size_t)N * F * 2;
    __hip_bfloat16* HXB1 = (__hip_bfloat16*)p; p += (size_t)N * F * 2;
    short* W0hi = (short*)p;                   p += (size_t)F * F * 2;
    short* W0lo = (short*)p;                   p += (size_t)F * F * 2;
    short* W1hi = (short*)p;                   p += (size_t)F * F * 2;
    short* W1lo = (short*)p;                   p += (size_t)F * F * 2;
    float* AL0  = (float*)p;                   p += (size_t)N * H * 4;
    float* AR0  = (float*)p;                   p += (size_t)N * H * 4;
    float* AL1  = (float*)p;                   p += (size_t)N * H * 4;
    float* AR1  = (float*)p;                   p += (size_t)N * H * 4;
    unsigned short* ssrc2u = (unsigned short*)p;
    p += (size_t)NBUCK * BUCKW * MAXDEG * 2;   // padded: bucket writeout covers 50176 nodes
    int* deg = (int*)p;                        p += (size_t)N * 4;
    unsigned int* buf = (unsigned int*)p;      p += (size_t)NBUCK * NABLK * SEGCAP * 4;
    int* cntmat = (int*)p;                     // [NABLK][NBUCK]

    // k_init: bucketA (atomic-free) + W0/W1 pre-split
    k_init<<<NABLK + 8, 256, 0, stream>>>(ei, E, cntmat, buf,
                                          W0, W0hi, W0lo, W1, W1hi, W1lo);

    // k_mid: bucketB (256 blocks, overlapped) + gemm0 (2 tiles/block)
    k_mid<<<NBUCK + GB, 256, 0, stream>>>(buf, cntmat, deg, ssrc2u, N,
                                          x, W0hi, W0lo, attl0, attr0,
                                          HXB0, AL0, AR0, ntiles);

    // k_ag1: FUSED layer-0 aggregation (16-lane groups, 1 round) + layer-1 GEMM
    k_ag1<<<ntiles, 256, 0, stream>>>(ssrc2u, deg, AL0, AR0, HXB0, b0,
                                      W1hi, W1lo, attl1, attr1,
                                      HXB1, AL1, AR1, ntiles);

    // layer-1 aggregation + head-mean (16-lane groups)
    k_aggr1<<<ntiles, 256, 0, stream>>>(ssrc2u, deg, AL1, AR1, HXB1, b1,
                                        (float*)d_out, N);
}

// Round 12
// 207.114 us; speedup vs baseline: 2.5120x; 1.0158x over previous
//
#include <hip/hip_runtime.h>
#include <hip/hip_bf16.h>

#define H 4
#define D 32
#define F 128      // H*D
#define MAXDEG 64  // slot capacity per dst (Poisson(16), max ~45)
#define PF 8       // gather prefetch depth (16-B rows in flight per lane)
#define NBUCK 256  // dst-range buckets for the 2-phase adjacency build
#define BUCKW 196  // dst range width per bucket (256*196 = 50176 >= N)
#define NABLK 128  // bucket phase-A blocks (E/128 = 6250 edges each)
#define SEGCAP 64  // per-(block,bucket) segment capacity (Binom mean 24.4 + 8 sigma)
#define GB    1563 // gemm blocks: 2 tiles/block over 3125 tiles
#define HXP   136  // LDS row stride (shorts), 16B-aligned rows
#define SWS   264  // sw group stride (floats): 264%32=8 -> groups on disjoint banks
#define SIS   68   // sidx group stride (u16): 68*2/4=34 dwords, 34%32=2 -> spread

typedef __attribute__((ext_vector_type(8))) short bf16x8;  // 8 bf16 (4 VGPRs)
typedef __attribute__((ext_vector_type(4))) float f32x4;

__device__ __forceinline__ short f2bf(float v) {
    __hip_bfloat16 h = __float2bfloat16(v);   // RNE
    return *reinterpret_cast<short*>(&h);
}
__device__ __forceinline__ float bf2f(short s) {
    __hip_bfloat16 h = *reinterpret_cast<__hip_bfloat16*>(&s);
    return __bfloat162float(h);
}

// ===========================================================================
// W split piece (fp32 -> bf16 hi/lo), one part = 1/4 of one matrix.
// ===========================================================================
__device__ __forceinline__
void wconv_part(int part8, const float* __restrict__ W0, short* __restrict__ W0hi,
                short* __restrict__ W0lo, const float* __restrict__ W1,
                short* __restrict__ W1hi, short* __restrict__ W1lo) {
    const int tid = threadIdx.x;
    const float* W  = (part8 < 4) ? W0 : W1;
    short* Whi = (part8 < 4) ? W0hi : W1hi;
    short* Wlo = (part8 < 4) ? W0lo : W1lo;
    const int part = part8 & 3;
    const int base = part * (F * F / 4);     // 4096 elems per part
    for (int i = base + tid * 4; i < base + F * F / 4; i += 1024) {
        float4 v = *reinterpret_cast<const float4*>(W + i);
        float vv[4] = {v.x, v.y, v.z, v.w};
        short hs[4], ls[4];
#pragma unroll
        for (int j = 0; j < 4; ++j) {
            hs[j] = f2bf(vv[j]);
            ls[j] = f2bf(vv[j] - bf2f(hs[j]));
        }
        *reinterpret_cast<short4*>(Whi + i) = make_short4(hs[0], hs[1], hs[2], hs[3]);
        *reinterpret_cast<short4*>(Wlo + i) = make_short4(ls[0], ls[1], ls[2], ls[3]);
    }
}

// ===========================================================================
// Bucket-sort phase A, ATOMIC-FREE in global memory (round-5 design).
// ===========================================================================
__device__ __forceinline__
void bucketA_body(int abid, const int* __restrict__ ei, int E,
                  int* __restrict__ cntmat, unsigned int* __restrict__ buf) {
    __shared__ int lcnt[NBUCK];
    const int tid = threadIdx.x;
    lcnt[tid] = 0;
    __syncthreads();
    const int per = ((E / NABLK) + 3) & ~3;      // 6252 (mult of 4)
    const int e0 = abid * per;
    const int e1 = min(e0 + per, E);
    for (int e = e0 + 4 * tid; e < e1; e += 1024) {
        int4 dv = *reinterpret_cast<const int4*>(ei + E + e);
        atomicAdd(&lcnt[dv.x / BUCKW], 1);
        atomicAdd(&lcnt[dv.y / BUCKW], 1);
        atomicAdd(&lcnt[dv.z / BUCKW], 1);
        atomicAdd(&lcnt[dv.w / BUCKW], 1);
    }
    __syncthreads();
    cntmat[abid * NBUCK + tid] = min(lcnt[tid], SEGCAP);
    lcnt[tid] = 0;
    __syncthreads();
    for (int e = e0 + 4 * tid; e < e1; e += 1024) {
        int4 sv = *reinterpret_cast<const int4*>(ei + e);
        int4 dv = *reinterpret_cast<const int4*>(ei + E + e);
        int ss[4] = {sv.x, sv.y, sv.z, sv.w};
        int dd[4] = {dv.x, dv.y, dv.z, dv.w};
#pragma unroll
        for (int j = 0; j < 4; ++j) {
            int b = dd[j] / BUCKW;
            int pos = atomicAdd(&lcnt[b], 1);   // LDS atomic only
            if (pos < SEGCAP)
                buf[((size_t)b * NABLK + abid) * SEGCAP + pos] =
                    (unsigned)ss[j] | ((unsigned)(dd[j] - b * BUCKW) << 16);
        }
    }
}

// k_init: bucketA [0,NABLK) | W-splits [NABLK, NABLK+8).
__global__ __launch_bounds__(256)
void k_init(const int* __restrict__ ei, int E, int* __restrict__ cntmat,
            unsigned int* __restrict__ buf,
            const float* __restrict__ W0, short* __restrict__ W0hi,
            short* __restrict__ W0lo, const float* __restrict__ W1,
            short* __restrict__ W1hi, short* __restrict__ W1lo) {
    const int bid = blockIdx.x;
    if (bid < NABLK)
        bucketA_body(bid, ei, E, cntmat, buf);
    else
        wconv_part(bid - NABLK, W0, W0hi, W0lo, W1, W1hi, W1lo);
}

// ===========================================================================
// Bucket phase B (device body): LDS arrays passed in (union'd in k_mid).
// ===========================================================================
__device__ __forceinline__
void bucketB_body(int b, const unsigned int* __restrict__ buf,
                  const int* __restrict__ cntmat, int* __restrict__ deg,
                  unsigned short* __restrict__ ssrc2u, int N,
                  int* cnt, int* scnt, unsigned short* slots) {
    const int tid = threadIdx.x;
    if (tid < BUCKW) cnt[tid] = 0;
    if (tid < NABLK) scnt[tid] = cntmat[tid * NBUCK + b];
    __syncthreads();
    const int a    = tid & (NABLK - 1);
    const int half = tid >> 7;            // 0 or 1
    const int mm   = scnt[a];
    const unsigned int* seg = buf + ((size_t)b * NABLK + a) * SEGCAP;
    for (int c = half * 4; c < mm; c += 8) {
        uint4 r = *reinterpret_cast<const uint4*>(seg + c);
        unsigned rr[4] = {r.x, r.y, r.z, r.w};
#pragma unroll
        for (int j = 0; j < 4; ++j) {
            if (c + j < mm) {
                int src  = rr[j] & 0xffff;
                int ldst = rr[j] >> 16;
                int slot = atomicAdd(&cnt[ldst], 1);   // LDS atomic
                if (slot < MAXDEG)
                    slots[ldst * MAXDEG + slot] = (unsigned short)src;
            }
        }
    }
    __syncthreads();
    uint4* dst = reinterpret_cast<uint4*>(ssrc2u + (size_t)b * BUCKW * MAXDEG);
    const uint4* s4 = reinterpret_cast<const uint4*>(slots);
    for (int i = tid; i < BUCKW * MAXDEG / 8; i += 256)
        dst[i] = s4[i];
    if (tid < BUCKW) {
        int node = b * BUCKW + tid;
        if (node < N) deg[node] = cnt[tid];
    }
}

// ===========================================================================
// GEMM shared pieces. MFMA layouts (m89, proven in prior rounds):
// A[m=lane&15][k=q*8+j], B[n=lane&15][k=q*8+j], C col=lane&15, row=q*4+reg.
// ===========================================================================
__device__ __forceinline__
void bsetup_pre(const short* __restrict__ Whi, const short* __restrict__ Wlo,
                int wave, int m, int q8, bf16x8 Bhi[2][4], bf16x8 Blo[2][4]) {
#pragma unroll
    for (int j = 0; j < 2; ++j) {
        const int fout = wave * 32 + j * 16 + m;
#pragma unroll
        for (int kc = 0; kc < 4; ++kc) {
            Bhi[j][kc] = *reinterpret_cast<const bf16x8*>(Whi + (size_t)fout * F + kc * 32 + q8);
            Blo[j][kc] = *reinterpret_cast<const bf16x8*>(Wlo + (size_t)fout * F + kc * 32 + q8);
        }
    }
}

__device__ __forceinline__
void loadA_f32(const float* __restrict__ X, int node0, int m, int q8, float4 r[8]) {
    const float* xp = X + (size_t)(node0 + m) * F + q8;
#pragma unroll
    for (int kc = 0; kc < 4; ++kc) {
        r[2 * kc]     = *reinterpret_cast<const float4*>(xp + kc * 32);
        r[2 * kc + 1] = *reinterpret_cast<const float4*>(xp + kc * 32 + 4);
    }
}

__device__ __forceinline__
void splitA(const float4 r[8], bf16x8 Ahi[4], bf16x8 Alo[4]) {
#pragma unroll
    for (int kc = 0; kc < 4; ++kc) {
        float xv[8] = {r[2 * kc].x, r[2 * kc].y, r[2 * kc].z, r[2 * kc].w,
                       r[2 * kc + 1].x, r[2 * kc + 1].y, r[2 * kc + 1].z, r[2 * kc + 1].w};
#pragma unroll
        for (int t2 = 0; t2 < 8; ++t2) {
            short hh = f2bf(xv[t2]);
            Ahi[kc][t2] = hh;
            Alo[kc][t2] = f2bf(xv[t2] - bf2f(hh));
        }
    }
}

// MFMA chain + epilogue for one 16-row tile; HXB tile -> LDS (row stride HXP).
__device__ __forceinline__
void mfma_epi(int tile, const bf16x8 Ahi[4], const bf16x8 Alo[4],
              const bf16x8 Bhi[2][4], const bf16x8 Blo[2][4],
              float alw0, float alw16, float arw0, float arw16,
              short* hxs, float* __restrict__ AL,
              float* __restrict__ AR, int wave, int m, int q) {
    const int node0 = tile * 16;
    f32x4 acc0 = {0.f, 0.f, 0.f, 0.f};
    f32x4 acc1 = {0.f, 0.f, 0.f, 0.f};
#pragma unroll
    for (int kc = 0; kc < 4; ++kc) {
        acc0 = __builtin_amdgcn_mfma_f32_16x16x32_bf16(Ahi[kc], Bhi[0][kc], acc0, 0, 0, 0);
        acc1 = __builtin_amdgcn_mfma_f32_16x16x32_bf16(Ahi[kc], Bhi[1][kc], acc1, 0, 0, 0);
        acc0 = __builtin_amdgcn_mfma_f32_16x16x32_bf16(Ahi[kc], Blo[0][kc], acc0, 0, 0, 0);
        acc1 = __builtin_amdgcn_mfma_f32_16x16x32_bf16(Ahi[kc], Blo[1][kc], acc1, 0, 0, 0);
        acc0 = __builtin_amdgcn_mfma_f32_16x16x32_bf16(Alo[kc], Bhi[0][kc], acc0, 0, 0, 0);
        acc1 = __builtin_amdgcn_mfma_f32_16x16x32_bf16(Alo[kc], Bhi[1][kc], acc1, 0, 0, 0);
    }
    const int row0 = node0 + q * 4;
    const int col0 = wave * 32 + m;
#pragma unroll
    for (int r = 0; r < 4; ++r) {
        hxs[(q * 4 + r) * HXP + col0]      = f2bf(acc0[r]);
        hxs[(q * 4 + r) * HXP + col0 + 16] = f2bf(acc1[r]);
        float pal = acc0[r] * alw0 + acc1[r] * alw16;
        float par = acc0[r] * arw0 + acc1[r] * arw16;
#pragma unroll
        for (int o = 1; o < 16; o <<= 1) {
            pal += __shfl_xor(pal, o);
            par += __shfl_xor(par, o);
        }
        if (m == 0) {
            AL[(size_t)(row0 + r) * H + wave] = pal;
            AR[(size_t)(row0 + r) * H + wave] = par;
        }
    }
}

// Coalesced tile writeout: thread t stores one dwordx4; 16 lanes per row.
__device__ __forceinline__
void hxb_writeout(const short* hxs, int tile, __hip_bfloat16* __restrict__ HXB) {
    const int tid = threadIdx.x;
    const int row = tid >> 4;
    const int col = (tid & 15) * 8;
    uint4 v = *reinterpret_cast<const uint4*>(hxs + row * HXP + col);
    *reinterpret_cast<uint4*>(reinterpret_cast<short*>(HXB) +
                              (size_t)(tile * 16 + row) * F + col) = v;
}

// Two-tile gemm0 body, fp32 A, pre-split W0.
__device__ __forceinline__
void gemm_pair_f32(int bid, const float* __restrict__ X,
                   const short* __restrict__ Whi, const short* __restrict__ Wlo,
                   const float* __restrict__ attl, const float* __restrict__ attr,
                   __hip_bfloat16* __restrict__ HXB, float* __restrict__ AL,
                   float* __restrict__ AR, int ntiles, short* hxs) {
    const int wave = threadIdx.x >> 6;
    const int lane = threadIdx.x & 63;
    const int m    = lane & 15;
    const int q    = lane >> 4;
    const int q8   = q * 8;
    bf16x8 Bhi[2][4], Blo[2][4];
    bsetup_pre(Whi, Wlo, wave, m, q8, Bhi, Blo);
    const float alw0  = attl[wave * 32 + m];
    const float alw16 = attl[wave * 32 + 16 + m];
    const float arw0  = attr[wave * 32 + m];
    const float arw16 = attr[wave * 32 + 16 + m];

    const int t0 = bid, t1 = bid + GB;
    const bool has1 = t1 < ntiles;
    float4 r0[8], r1[8];
    loadA_f32(X, t0 * 16, m, q8, r0);
    if (has1) loadA_f32(X, t1 * 16, m, q8, r1);   // prefetch
    bf16x8 Ahi[4], Alo[4];
    splitA(r0, Ahi, Alo);
    mfma_epi(t0, Ahi, Alo, Bhi, Blo, alw0, alw16, arw0, arw16, hxs, AL, AR, wave, m, q);
    if (has1) {
        splitA(r1, Ahi, Alo);
        mfma_epi(t1, Ahi, Alo, Bhi, Blo, alw0, alw16, arw0, arw16,
                 hxs + 16 * HXP, AL, AR, wave, m, q);
    }
    __syncthreads();
    hxb_writeout(hxs, t0, HXB);
    if (has1) hxb_writeout(hxs + 16 * HXP, t1, HXB);
}

// k_mid: bucketB [0,NBUCK) runs concurrently with gemm0 [NBUCK, NBUCK+GB).
__global__ __launch_bounds__(256)
void k_mid(const unsigned int* __restrict__ buf, const int* __restrict__ cntmat,
           int* __restrict__ deg, unsigned short* __restrict__ ssrc2u, int N,
           const float* __restrict__ X, const short* __restrict__ W0hi,
           const short* __restrict__ W0lo, const float* __restrict__ attl0,
           const float* __restrict__ attr0, __hip_bfloat16* __restrict__ HXB,
           float* __restrict__ AL, float* __restrict__ AR, int ntiles) {
    __shared__ union {
        struct {
            int cnt[BUCKW];
            int scnt[NABLK];
            unsigned short slots[BUCKW * MAXDEG];
        } bb;                                 // 26384 B
        short hxs[2 * 16 * HXP];              //  8704 B
    } sm;
    const int bid = blockIdx.x;
    if (bid < NBUCK)
        bucketB_body(bid, buf, cntmat, deg, ssrc2u, N,
                     sm.bb.cnt, sm.bb.scnt, sm.bb.slots);
    else
        gemm_pair_f32(bid - NBUCK, X, W0hi, W0lo, attl0, attr0, HXB, AL, AR,
                      ntiles, sm.hxs);
}

// ===========================================================================
// 16-lane-group aggregation with BANK-PADDED LDS (round-11 counter: 1.21M
// SQ_LDS_BANK_CONFLICT from group strides ≡ 0 mod 32 banks — sw stride 256
// floats and sidx stride 64 ints put all 4 groups of a wave on the same
// bank, 4-8 way). sw stride SWS=264 (8-bank group offset, h-addresses
// disjoint across groups); sidx u16 stride SIS=68. Arithmetic unchanged.
// ===========================================================================
__device__ __forceinline__
int stage_node16(int g, int lt, int n, const unsigned short* __restrict__ ssrc2u,
                 const int* __restrict__ deg, const float* __restrict__ AL,
                 const float4 ar4, unsigned short* sidx, float* sw) {
    const int cnt  = min(deg[n], MAXDEG);
    const int rcnt = (cnt + PF - 1) & ~(PF - 1);
    for (int t2 = lt; t2 < rcnt; t2 += 16) {
        if (t2 < cnt) {
            int s = ssrc2u[(size_t)n * MAXDEG + t2];
            sidx[g * SIS + t2] = (unsigned short)s;
            float4 al4 = *reinterpret_cast<const float4*>(AL + (size_t)s * H);
            float a0 = al4.x + ar4.x; a0 = a0 > 0.f ? a0 : 0.2f * a0;
            float a1 = al4.y + ar4.y; a1 = a1 > 0.f ? a1 : 0.2f * a1;
            float a2 = al4.z + ar4.z; a2 = a2 > 0.f ? a2 : 0.2f * a2;
            float a3 = al4.w + ar4.w; a3 = a3 > 0.f ? a3 : 0.2f * a3;
            sw[g * SWS + t2 * H + 0] = __expf(a0);
            sw[g * SWS + t2 * H + 1] = __expf(a1);
            sw[g * SWS + t2 * H + 2] = __expf(a2);
            sw[g * SWS + t2 * H + 3] = __expf(a3);
        } else {
            sidx[g * SIS + t2] = 0;
            sw[g * SWS + t2 * H + 0] = 0.f; sw[g * SWS + t2 * H + 1] = 0.f;
            sw[g * SWS + t2 * H + 2] = 0.f; sw[g * SWS + t2 * H + 3] = 0.f;
        }
    }
    __builtin_amdgcn_wave_barrier();
    return rcnt;
}

__device__ __forceinline__
void gather16(int g, int lt, int rcnt, const __hip_bfloat16* __restrict__ HXB,
              const unsigned short* sidx, const float* sw,
              float a[8], float& wsum) {
    const int h = lt >> 2;
    const unsigned short* hx = reinterpret_cast<const unsigned short*>(HXB);
    for (int base = 0; base < rcnt; base += PF) {
        uint4 v[PF];
#pragma unroll
        for (int j = 0; j < PF; ++j) {
            int s = sidx[g * SIS + base + j];
            v[j] = *reinterpret_cast<const uint4*>(hx + (size_t)s * F + 8 * lt);
        }
#pragma unroll
        for (int j = 0; j < PF; ++j) {
            float w = sw[g * SWS + (base + j) * H + h];
            unsigned ww[4] = {v[j].x, v[j].y, v[j].z, v[j].w};
#pragma unroll
            for (int k = 0; k < 4; ++k) {
                a[2 * k]     += w * bf2f((short)(ww[k] & 0xffff));
                a[2 * k + 1] += w * bf2f((short)(ww[k] >> 16));
            }
            wsum += w;
        }
    }
}

// ===========================================================================
// k_ag1: FUSED layer-0 aggregation + layer-1 GEMM, one 16-node tile per block.
// Phase 1 (ONE round, 16 16-lane groups): gather + relu + split-bf16 X1 rows
// to LDS ONLY. Phase 2: MFMA tile with A from LDS -> HXB1/AL1/AR1.
// ===========================================================================
__global__ __launch_bounds__(256)
void k_ag1(const unsigned short* __restrict__ ssrc2u, const int* __restrict__ deg,
           const float* __restrict__ AL0, const float* __restrict__ AR0,
           const __hip_bfloat16* __restrict__ HXB0, const float* __restrict__ b0,
           const short* __restrict__ W1hi, const short* __restrict__ W1lo,
           const float* __restrict__ attl1, const float* __restrict__ attr1,
           __hip_bfloat16* __restrict__ HXB1, float* __restrict__ AL1,
           float* __restrict__ AR1, int ntiles) {
    __shared__ unsigned short sidx[16 * SIS];   // 2176 B
    __shared__ float sw[16 * SWS];              // 16896 B; reused as hxs
    __shared__ short x1h[16 * HXP];             // 4352 B
    __shared__ short x1l[16 * HXP];             // 4352 B
    const int tid  = threadIdx.x;
    const int g    = tid >> 4;
    const int lt   = tid & 15;
    const int tile = blockIdx.x;

    // ---- phase 1: aggregate 16 nodes in one round, X1 -> LDS -------------
    {
        const int n = tile * 16 + g;
        const float4 ar4 = *reinterpret_cast<const float4*>(AR0 + (size_t)n * H);
        int rcnt = stage_node16(g, lt, n, ssrc2u, deg, AL0, ar4, sidx, sw);
        float a[8] = {0.f, 0.f, 0.f, 0.f, 0.f, 0.f, 0.f, 0.f};
        float ws = 0.f;
        gather16(g, lt, rcnt, HXB0, sidx, sw, a, ws);
        float inv = 1.f / (ws + 1e-9f);
        const float4 b4a = *reinterpret_cast<const float4*>(b0 + 8 * lt);
        const float4 b4b = *reinterpret_cast<const float4*>(b0 + 8 * lt + 4);
        float bb[8] = {b4a.x, b4a.y, b4a.z, b4a.w, b4b.x, b4b.y, b4b.z, b4b.w};
        unsigned hw[4], lw[4];
#pragma unroll
        for (int k = 0; k < 4; ++k) {
            float o0 = fmaxf(a[2 * k] * inv + bb[2 * k], 0.f);
            float o1 = fmaxf(a[2 * k + 1] * inv + bb[2 * k + 1], 0.f);
            short h0 = f2bf(o0), h1 = f2bf(o1);
            short l0 = f2bf(o0 - bf2f(h0)), l1 = f2bf(o1 - bf2f(h1));
            hw[k] = (unsigned)(unsigned short)h0 | ((unsigned)(unsigned short)h1 << 16);
            lw[k] = (unsigned)(unsigned short)l0 | ((unsigned)(unsigned short)l1 << 16);
        }
        uint4 hv = {hw[0], hw[1], hw[2], hw[3]};
        uint4 lv = {lw[0], lw[1], lw[2], lw[3]};
        *reinterpret_cast<uint4*>(x1h + g * HXP + 8 * lt) = hv;
        *reinterpret_cast<uint4*>(x1l + g * HXP + 8 * lt) = lv;
    }
    __syncthreads();   // X1 tile complete in LDS; sw dead from here

    // ---- phase 2: layer-1 GEMM tile, A from LDS ---------------------------
    short* hxs = reinterpret_cast<short*>(sw);   // reuse (safe post-barrier)
    {
        const int wave = tid >> 6;
        const int lane = tid & 63;
        const int m    = lane & 15;
        const int q    = lane >> 4;
        const int q8   = q * 8;
        bf16x8 Bhi[2][4], Blo[2][4];
        bsetup_pre(W1hi, W1lo, wave, m, q8, Bhi, Blo);
        const float alw0  = attl1[wave * 32 + m];
        const float alw16 = attl1[wave * 32 + 16 + m];
        const float arw0  = attr1[wave * 32 + m];
        const float arw16 = attr1[wave * 32 + 16 + m];
        bf16x8 Ahi[4], Alo[4];
#pragma unroll
        for (int kc = 0; kc < 4; ++kc) {
            Ahi[kc] = *reinterpret_cast<const bf16x8*>(x1h + m * HXP + kc * 32 + q8);
            Alo[kc] = *reinterpret_cast<const bf16x8*>(x1l + m * HXP + kc * 32 + q8);
        }
        mfma_epi(tile, Ahi, Alo, Bhi, Blo, alw0, alw16, arw0, arw16,
                 hxs, AL1, AR1, wave, m, q);
    }
    __syncthreads();
    hxb_writeout(hxs, tile, HXB1);
}

// k_aggr1: layer-1 aggregation + head-mean (16-lane groups, 16 nodes/block).
// Head grouping ((h0+h1)+(h2+h3)) via xor4 then xor8 — bit-exact vs round 9.
__global__ __launch_bounds__(256)
void k_aggr1(const unsigned short* __restrict__ ssrc2u, const int* __restrict__ deg,
             const float* __restrict__ AL, const float* __restrict__ AR,
             const __hip_bfloat16* __restrict__ HXB, const float* __restrict__ bias,
             float* __restrict__ out, int N) {
    __shared__ unsigned short sidx[16 * SIS];
    __shared__ float sw[16 * SWS];
    const int tid = threadIdx.x;
    const int g   = tid >> 4;
    const int lt  = tid & 15;
    const int n   = blockIdx.x * 16 + g;   // N = 50000 = 3125*16, no tail
    const float4 ar4 = *reinterpret_cast<const float4*>(AR + (size_t)n * H);
    int rcnt = stage_node16(g, lt, n, ssrc2u, deg, AL, ar4, sidx, sw);
    float a[8] = {0.f, 0.f, 0.f, 0.f, 0.f, 0.f, 0.f, 0.f};
    float ws = 0.f;
    gather16(g, lt, rcnt, HXB, sidx, sw, a, ws);
    float inv = 1.f / (ws + 1e-9f);
    float v[8];
#pragma unroll
    for (int k = 0; k < 8; ++k) {
        v[k] = a[k] * inv;
        v[k] += __shfl_xor(v[k], 4);    // h0+h1, h2+h3
        v[k] += __shfl_xor(v[k], 8);    // (h0+h1)+(h2+h3)
    }
    if (lt < 4) {
        const float4 b4a = *reinterpret_cast<const float4*>(bias + 8 * lt);
        const float4 b4b = *reinterpret_cast<const float4*>(bias + 8 * lt + 4);
        float4 o0, o1;
        o0.x = 0.25f * v[0] + b4a.x;
        o0.y = 0.25f * v[1] + b4a.y;
        o0.z = 0.25f * v[2] + b4a.z;
        o0.w = 0.25f * v[3] + b4a.w;
        o1.x = 0.25f * v[4] + b4b.x;
        o1.y = 0.25f * v[5] + b4b.y;
        o1.z = 0.25f * v[6] + b4b.z;
        o1.w = 0.25f * v[7] + b4b.w;
        *reinterpret_cast<float4*>(out + (size_t)n * D + 8 * lt)     = o0;
        *reinterpret_cast<float4*>(out + (size_t)n * D + 8 * lt + 4) = o1;
    }
}

// ===========================================================================
extern "C" void kernel_launch(void* const* d_in, const int* in_sizes, int n_in,
                              void* d_out, int out_size, void* d_ws, size_t ws_size,
                              hipStream_t stream) {
    const float* x     = (const float*)d_in[0];
    const int*   ei    = (const int*)d_in[1];
    const float* W0    = (const float*)d_in[2];
    const float* attl0 = (const float*)d_in[3];
    const float* attr0 = (const float*)d_in[4];
    const float* b0    = (const float*)d_in[5];
    const float* W1    = (const float*)d_in[6];
    const float* attl1 = (const float*)d_in[7];
    const float* attr1 = (const float*)d_in[8];
    const float* b1    = (const float*)d_in[9];

    const int N = in_sizes[0] / F;   // 50000
    const int E = in_sizes[1] / 2;   // 800000
    const int ntiles = N / 16;       // 3125

    // Workspace: HXB0 | HXB1 | W0hi | W0lo | W1hi | W1lo | AL0 | AR0 |
    //            AL1 | AR1 | ssrc2u (PADDED NBUCK*BUCKW nodes) | deg | buf | cntmat
    char* p = (char*)d_ws;
    __hip_bfloat16* HXB0 = (__hip_bfloat16*)p; p += (size_t)N * F * 2;
    __hip_bfloat16* HXB1 = (__hip_bfloat16*)p; p += (size_t)N * F * 2;
    short* W0hi = (short*)p;                   p += (size_t)F * F * 2;
    short* W0lo = (short*)p;                   p += (size_t)F * F * 2;
    short* W1hi = (short*)p;                   p += (size_t)F * F * 2;
    short* W1lo = (short*)p;                   p += (size_t)F * F * 2;
    float* AL0  = (float*)p;                   p += (size_t)N * H * 4;
    float* AR0  = (float*)p;                   p += (size_t)N * H * 4;
    float* AL1  = (float*)p;                   p += (size_t)N * H * 4;
    float* AR1  = (float*)p;                   p += (size_t)N * H * 4;
    unsigned short* ssrc2u = (unsigned short*)p;
    p += (size_t)NBUCK * BUCKW * MAXDEG * 2;   // padded: bucket writeout covers 50176 nodes
    int* deg = (int*)p;                        p += (size_t)N * 4;
    unsigned int* buf = (unsigned int*)p;      p += (size_t)NBUCK * NABLK * SEGCAP * 4;
    int* cntmat = (int*)p;                     // [NABLK][NBUCK]

    // k_init: bucketA (atomic-free) + W0/W1 pre-split
    k_init<<<NABLK + 8, 256, 0, stream>>>(ei, E, cntmat, buf,
                                          W0, W0hi, W0lo, W1, W1hi, W1lo);

    // k_mid: bucketB (256 blocks, overlapped) + gemm0 (2 tiles/block)
    k_mid<<<NBUCK + GB, 256, 0, stream>>>(buf, cntmat, deg, ssrc2u, N,
                                          x, W0hi, W0lo, attl0, attr0,
                                          HXB0, AL0, AR0, ntiles);

    // k_ag1: FUSED layer-0 aggregation (bank-padded LDS) + layer-1 GEMM
    k_ag1<<<ntiles, 256, 0, stream>>>(ssrc2u, deg, AL0, AR0, HXB0, b0,
                                      W1hi, W1lo, attl1, attr1,
                                      HXB1, AL1, AR1, ntiles);

    // layer-1 aggregation + head-mean (bank-padded LDS)
    k_aggr1<<<ntiles, 256, 0, stream>>>(ssrc2u, deg, AL1, AR1, HXB1, b1,
                                        (float*)d_out, N);
}

// Round 13
// 204.007 us; speedup vs baseline: 2.5503x; 1.0152x over previous
//
#include <hip/hip_runtime.h>
#include <hip/hip_bf16.h>

#define H 4
#define D 32
#define F 128      // H*D
#define MAXDEG 64  // slot capacity per dst (Poisson(16), max ~45)
#define PF 8       // gather prefetch depth (16-B rows in flight per lane)
#define NBUCK 256  // dst-range buckets for the 2-phase adjacency build
#define BUCKW 196  // dst range width per bucket (256*196 = 50176 >= N)
#define NABLK 128  // bucket phase-A blocks (E/128 = 6250 edges each)
#define SEGCAP 64  // per-(block,bucket) segment capacity (Binom mean 24.4 + 8 sigma)
#define GB    1563 // gemm blocks: 2 tiles/block over 3125 tiles
#define HXP   136  // LDS row stride (shorts), 16B-aligned rows
#define SIS   68   // sidx group stride (u16)

typedef __attribute__((ext_vector_type(8))) short bf16x8;  // 8 bf16 (4 VGPRs)
typedef __attribute__((ext_vector_type(4))) float f32x4;

__device__ __forceinline__ short f2bf(float v) {
    __hip_bfloat16 h = __float2bfloat16(v);   // RNE
    return *reinterpret_cast<short*>(&h);
}
__device__ __forceinline__ float bf2f(short s) {
    __hip_bfloat16 h = *reinterpret_cast<__hip_bfloat16*>(&s);
    return __bfloat162float(h);
}

// ===========================================================================
// W split piece (fp32 -> bf16 hi/lo), one part = 1/4 of one matrix.
// ===========================================================================
__device__ __forceinline__
void wconv_part(int part8, const float* __restrict__ W0, short* __restrict__ W0hi,
                short* __restrict__ W0lo, const float* __restrict__ W1,
                short* __restrict__ W1hi, short* __restrict__ W1lo) {
    const int tid = threadIdx.x;
    const float* W  = (part8 < 4) ? W0 : W1;
    short* Whi = (part8 < 4) ? W0hi : W1hi;
    short* Wlo = (part8 < 4) ? W0lo : W1lo;
    const int part = part8 & 3;
    const int base = part * (F * F / 4);     // 4096 elems per part
    for (int i = base + tid * 4; i < base + F * F / 4; i += 1024) {
        float4 v = *reinterpret_cast<const float4*>(W + i);
        float vv[4] = {v.x, v.y, v.z, v.w};
        short hs[4], ls[4];
#pragma unroll
        for (int j = 0; j < 4; ++j) {
            hs[j] = f2bf(vv[j]);
            ls[j] = f2bf(vv[j] - bf2f(hs[j]));
        }
        *reinterpret_cast<short4*>(Whi + i) = make_short4(hs[0], hs[1], hs[2], hs[3]);
        *reinterpret_cast<short4*>(Wlo + i) = make_short4(ls[0], ls[1], ls[2], ls[3]);
    }
}

// ===========================================================================
// Bucket-sort phase A, ATOMIC-FREE in global memory (round-5 design).
// ===========================================================================
__device__ __forceinline__
void bucketA_body(int abid, const int* __restrict__ ei, int E,
                  int* __restrict__ cntmat, unsigned int* __restrict__ buf) {
    __shared__ int lcnt[NBUCK];
    const int tid = threadIdx.x;
    lcnt[tid] = 0;
    __syncthreads();
    const int per = ((E / NABLK) + 3) & ~3;      // 6252 (mult of 4)
    const int e0 = abid * per;
    const int e1 = min(e0 + per, E);
    for (int e = e0 + 4 * tid; e < e1; e += 1024) {
        int4 dv = *reinterpret_cast<const int4*>(ei + E + e);
        atomicAdd(&lcnt[dv.x / BUCKW], 1);
        atomicAdd(&lcnt[dv.y / BUCKW], 1);
        atomicAdd(&lcnt[dv.z / BUCKW], 1);
        atomicAdd(&lcnt[dv.w / BUCKW], 1);
    }
    __syncthreads();
    cntmat[abid * NBUCK + tid] = min(lcnt[tid], SEGCAP);
    lcnt[tid] = 0;
    __syncthreads();
    for (int e = e0 + 4 * tid; e < e1; e += 1024) {
        int4 sv = *reinterpret_cast<const int4*>(ei + e);
        int4 dv = *reinterpret_cast<const int4*>(ei + E + e);
        int ss[4] = {sv.x, sv.y, sv.z, sv.w};
        int dd[4] = {dv.x, dv.y, dv.z, dv.w};
#pragma unroll
        for (int j = 0; j < 4; ++j) {
            int b = dd[j] / BUCKW;
            int pos = atomicAdd(&lcnt[b], 1);   // LDS atomic only
            if (pos < SEGCAP)
                buf[((size_t)b * NABLK + abid) * SEGCAP + pos] =
                    (unsigned)ss[j] | ((unsigned)(dd[j] - b * BUCKW) << 16);
        }
    }
}

// k_init: bucketA [0,NABLK) | W-splits [NABLK, NABLK+8).
__global__ __launch_bounds__(256)
void k_init(const int* __restrict__ ei, int E, int* __restrict__ cntmat,
            unsigned int* __restrict__ buf,
            const float* __restrict__ W0, short* __restrict__ W0hi,
            short* __restrict__ W0lo, const float* __restrict__ W1,
            short* __restrict__ W1hi, short* __restrict__ W1lo) {
    const int bid = blockIdx.x;
    if (bid < NABLK)
        bucketA_body(bid, ei, E, cntmat, buf);
    else
        wconv_part(bid - NABLK, W0, W0hi, W0lo, W1, W1hi, W1lo);
}

// ===========================================================================
// Bucket phase B (device body): LDS arrays passed in (union'd in k_mid).
// ===========================================================================
__device__ __forceinline__
void bucketB_body(int b, const unsigned int* __restrict__ buf,
                  const int* __restrict__ cntmat, int* __restrict__ deg,
                  unsigned short* __restrict__ ssrc2u, int N,
                  int* cnt, int* scnt, unsigned short* slots) {
    const int tid = threadIdx.x;
    if (tid < BUCKW) cnt[tid] = 0;
    if (tid < NABLK) scnt[tid] = cntmat[tid * NBUCK + b];
    __syncthreads();
    const int a    = tid & (NABLK - 1);
    const int half = tid >> 7;            // 0 or 1
    const int mm   = scnt[a];
    const unsigned int* seg = buf + ((size_t)b * NABLK + a) * SEGCAP;
    for (int c = half * 4; c < mm; c += 8) {
        uint4 r = *reinterpret_cast<const uint4*>(seg + c);
        unsigned rr[4] = {r.x, r.y, r.z, r.w};
#pragma unroll
        for (int j = 0; j < 4; ++j) {
            if (c + j < mm) {
                int src  = rr[j] & 0xffff;
                int ldst = rr[j] >> 16;
                int slot = atomicAdd(&cnt[ldst], 1);   // LDS atomic
                if (slot < MAXDEG)
                    slots[ldst * MAXDEG + slot] = (unsigned short)src;
            }
        }
    }
    __syncthreads();
    uint4* dst = reinterpret_cast<uint4*>(ssrc2u + (size_t)b * BUCKW * MAXDEG);
    const uint4* s4 = reinterpret_cast<const uint4*>(slots);
    for (int i = tid; i < BUCKW * MAXDEG / 8; i += 256)
        dst[i] = s4[i];
    if (tid < BUCKW) {
        int node = b * BUCKW + tid;
        if (node < N) deg[node] = cnt[tid];
    }
}

// ===========================================================================
// GEMM shared pieces. MFMA layouts (m89, proven in prior rounds):
// A[m=lane&15][k=q*8+j], B[n=lane&15][k=q*8+j], C col=lane&15, row=q*4+reg.
// ===========================================================================
__device__ __forceinline__
void bsetup_pre(const short* __restrict__ Whi, const short* __restrict__ Wlo,
                int wave, int m, int q8, bf16x8 Bhi[2][4], bf16x8 Blo[2][4]) {
#pragma unroll
    for (int j = 0; j < 2; ++j) {
        const int fout = wave * 32 + j * 16 + m;
#pragma unroll
        for (int kc = 0; kc < 4; ++kc) {
            Bhi[j][kc] = *reinterpret_cast<const bf16x8*>(Whi + (size_t)fout * F + kc * 32 + q8);
            Blo[j][kc] = *reinterpret_cast<const bf16x8*>(Wlo + (size_t)fout * F + kc * 32 + q8);
        }
    }
}

__device__ __forceinline__
void loadA_f32(const float* __restrict__ X, int node0, int m, int q8, float4 r[8]) {
    const float* xp = X + (size_t)(node0 + m) * F + q8;
#pragma unroll
    for (int kc = 0; kc < 4; ++kc) {
        r[2 * kc]     = *reinterpret_cast<const float4*>(xp + kc * 32);
        r[2 * kc + 1] = *reinterpret_cast<const float4*>(xp + kc * 32 + 4);
    }
}

__device__ __forceinline__
void splitA(const float4 r[8], bf16x8 Ahi[4], bf16x8 Alo[4]) {
#pragma unroll
    for (int kc = 0; kc < 4; ++kc) {
        float xv[8] = {r[2 * kc].x, r[2 * kc].y, r[2 * kc].z, r[2 * kc].w,
                       r[2 * kc + 1].x, r[2 * kc + 1].y, r[2 * kc + 1].z, r[2 * kc + 1].w};
#pragma unroll
        for (int t2 = 0; t2 < 8; ++t2) {
            short hh = f2bf(xv[t2]);
            Ahi[kc][t2] = hh;
            Alo[kc][t2] = f2bf(xv[t2] - bf2f(hh));
        }
    }
}

// MFMA chain + epilogue for one 16-row tile; HXB tile -> LDS (row stride HXP).
__device__ __forceinline__
void mfma_epi(int tile, const bf16x8 Ahi[4], const bf16x8 Alo[4],
              const bf16x8 Bhi[2][4], const bf16x8 Blo[2][4],
              float alw0, float alw16, float arw0, float arw16,
              short* hxs, float* __restrict__ AL,
              float* __restrict__ AR, int wave, int m, int q) {
    const int node0 = tile * 16;
    f32x4 acc0 = {0.f, 0.f, 0.f, 0.f};
    f32x4 acc1 = {0.f, 0.f, 0.f, 0.f};
#pragma unroll
    for (int kc = 0; kc < 4; ++kc) {
        acc0 = __builtin_amdgcn_mfma_f32_16x16x32_bf16(Ahi[kc], Bhi[0][kc], acc0, 0, 0, 0);
        acc1 = __builtin_amdgcn_mfma_f32_16x16x32_bf16(Ahi[kc], Bhi[1][kc], acc1, 0, 0, 0);
        acc0 = __builtin_amdgcn_mfma_f32_16x16x32_bf16(Ahi[kc], Blo[0][kc], acc0, 0, 0, 0);
        acc1 = __builtin_amdgcn_mfma_f32_16x16x32_bf16(Ahi[kc], Blo[1][kc], acc1, 0, 0, 0);
        acc0 = __builtin_amdgcn_mfma_f32_16x16x32_bf16(Alo[kc], Bhi[0][kc], acc0, 0, 0, 0);
        acc1 = __builtin_amdgcn_mfma_f32_16x16x32_bf16(Alo[kc], Bhi[1][kc], acc1, 0, 0, 0);
    }
    const int row0 = node0 + q * 4;
    const int col0 = wave * 32 + m;
#pragma unroll
    for (int r = 0; r < 4; ++r) {
        hxs[(q * 4 + r) * HXP + col0]      = f2bf(acc0[r]);
        hxs[(q * 4 + r) * HXP + col0 + 16] = f2bf(acc1[r]);
        float pal = acc0[r] * alw0 + acc1[r] * alw16;
        float par = acc0[r] * arw0 + acc1[r] * arw16;
#pragma unroll
        for (int o = 1; o < 16; o <<= 1) {
            pal += __shfl_xor(pal, o);
            par += __shfl_xor(par, o);
        }
        if (m == 0) {
            AL[(size_t)(row0 + r) * H + wave] = pal;
            AR[(size_t)(row0 + r) * H + wave] = par;
        }
    }
}

// Coalesced tile writeout: thread t stores one dwordx4; 16 lanes per row.
__device__ __forceinline__
void hxb_writeout(const short* hxs, int tile, __hip_bfloat16* __restrict__ HXB) {
    const int tid = threadIdx.x;
    const int row = tid >> 4;
    const int col = (tid & 15) * 8;
    uint4 v = *reinterpret_cast<const uint4*>(hxs + row * HXP + col);
    *reinterpret_cast<uint4*>(reinterpret_cast<short*>(HXB) +
                              (size_t)(tile * 16 + row) * F + col) = v;
}

// Two-tile gemm0 body, fp32 A, pre-split W0.
__device__ __forceinline__
void gemm_pair_f32(int bid, const float* __restrict__ X,
                   const short* __restrict__ Whi, const short* __restrict__ Wlo,
                   const float* __restrict__ attl, const float* __restrict__ attr,
                   __hip_bfloat16* __restrict__ HXB, float* __restrict__ AL,
                   float* __restrict__ AR, int ntiles, short* hxs) {
    const int wave = threadIdx.x >> 6;
    const int lane = threadIdx.x & 63;
    const int m    = lane & 15;
    const int q    = lane >> 4;
    const int q8   = q * 8;
    bf16x8 Bhi[2][4], Blo[2][4];
    bsetup_pre(Whi, Wlo, wave, m, q8, Bhi, Blo);
    const float alw0  = attl[wave * 32 + m];
    const float alw16 = attl[wave * 32 + 16 + m];
    const float arw0  = attr[wave * 32 + m];
    const float arw16 = attr[wave * 32 + 16 + m];

    const int t0 = bid, t1 = bid + GB;
    const bool has1 = t1 < ntiles;
    float4 r0[8], r1[8];
    loadA_f32(X, t0 * 16, m, q8, r0);
    if (has1) loadA_f32(X, t1 * 16, m, q8, r1);   // prefetch
    bf16x8 Ahi[4], Alo[4];
    splitA(r0, Ahi, Alo);
    mfma_epi(t0, Ahi, Alo, Bhi, Blo, alw0, alw16, arw0, arw16, hxs, AL, AR, wave, m, q);
    if (has1) {
        splitA(r1, Ahi, Alo);
        mfma_epi(t1, Ahi, Alo, Bhi, Blo, alw0, alw16, arw0, arw16,
                 hxs + 16 * HXP, AL, AR, wave, m, q);
    }
    __syncthreads();
    hxb_writeout(hxs, t0, HXB);
    if (has1) hxb_writeout(hxs + 16 * HXP, t1, HXB);
}

// k_mid: bucketB [0,NBUCK) runs concurrently with gemm0 [NBUCK, NBUCK+GB).
__global__ __launch_bounds__(256)
void k_mid(const unsigned int* __restrict__ buf, const int* __restrict__ cntmat,
           int* __restrict__ deg, unsigned short* __restrict__ ssrc2u, int N,
           const float* __restrict__ X, const short* __restrict__ W0hi,
           const short* __restrict__ W0lo, const float* __restrict__ attl0,
           const float* __restrict__ attr0, __hip_bfloat16* __restrict__ HXB,
           float* __restrict__ AL, float* __restrict__ AR, int ntiles) {
    __shared__ union {
        struct {
            int cnt[BUCKW];
            int scnt[NABLK];
            unsigned short slots[BUCKW * MAXDEG];
        } bb;                                 // 26384 B
        short hxs[2 * 16 * HXP];              //  8704 B
    } sm;
    const int bid = blockIdx.x;
    if (bid < NBUCK)
        bucketB_body(bid, buf, cntmat, deg, ssrc2u, N,
                     sm.bb.cnt, sm.bb.scnt, sm.bb.slots);
    else
        gemm_pair_f32(bid - NBUCK, X, W0hi, W0lo, attl0, attr0, HXB, AL, AR,
                      ntiles, sm.hxs);
}

// ===========================================================================
// 16-lane-group aggregation, INLINE-EXP variant (round-12 evidence: k_ag1 at
// 34% occupancy, ~11% of per-CU L2 BW -> latency-bound; the 16.9 KB sw LDS
// cache was the occupancy cap at 5 blocks/CU). Weights are recomputed in
// registers during the gather — lane lt (head h=lt>>2) loads AL[s*4+h] (4 B,
// L2-hot) next to its 16-B HX row: w = exp(lrelu(al+ar_h)), w=0 for padding.
// Bit-identical arithmetic and accumulation order; LDS -> 13.1 KB (8 blk/CU).
// ===========================================================================
__device__ __forceinline__
int2 stage_idx16(int g, int lt, int n, const unsigned short* __restrict__ ssrc2u,
                 const int* __restrict__ deg, unsigned short* sidx) {
    const int cnt  = min(deg[n], MAXDEG);
    const int rcnt = (cnt + PF - 1) & ~(PF - 1);
    for (int t2 = lt; t2 < rcnt; t2 += 16)
        sidx[g * SIS + t2] =
            (t2 < cnt) ? ssrc2u[(size_t)n * MAXDEG + t2] : (unsigned short)0;
    __builtin_amdgcn_wave_barrier();
    return make_int2(cnt, rcnt);
}

__device__ __forceinline__
void gather16(int g, int lt, int cnt, int rcnt,
              const __hip_bfloat16* __restrict__ HXB,
              const float* __restrict__ AL, float ar_h,
              const unsigned short* sidx, float a[8], float& wsum) {
    const int h = lt >> 2;
    const unsigned short* hx = reinterpret_cast<const unsigned short*>(HXB);
    for (int base = 0; base < rcnt; base += PF) {
        uint4 v[PF];
        float alv[PF];
#pragma unroll
        for (int j = 0; j < PF; ++j) {
            int s = sidx[g * SIS + base + j];
            v[j]   = *reinterpret_cast<const uint4*>(hx + (size_t)s * F + 8 * lt);
            alv[j] = AL[s * H + h];
        }
#pragma unroll
        for (int j = 0; j < PF; ++j) {
            float t = alv[j] + ar_h;
            t = t > 0.f ? t : 0.2f * t;
            float w = (base + j < cnt) ? __expf(t) : 0.f;
            unsigned ww[4] = {v[j].x, v[j].y, v[j].z, v[j].w};
#pragma unroll
            for (int k = 0; k < 4; ++k) {
                a[2 * k]     += w * bf2f((short)(ww[k] & 0xffff));
                a[2 * k + 1] += w * bf2f((short)(ww[k] >> 16));
            }
            wsum += w;
        }
    }
}

// ===========================================================================
// k_ag1: FUSED layer-0 aggregation + layer-1 GEMM, one 16-node tile per block.
// Phase 1 (ONE round, 16 16-lane groups, inline-exp): gather + relu +
// split-bf16 X1 rows to LDS ONLY. Phase 2: MFMA tile with A from LDS.
// LDS: union{sidx, hxs} 4.4 KB + x1h/x1l 8.7 KB = 13.1 KB -> 8 blocks/CU.
// ===========================================================================
__global__ __launch_bounds__(256)
void k_ag1(const unsigned short* __restrict__ ssrc2u, const int* __restrict__ deg,
           const float* __restrict__ AL0, const float* __restrict__ AR0,
           const __hip_bfloat16* __restrict__ HXB0, const float* __restrict__ b0,
           const short* __restrict__ W1hi, const short* __restrict__ W1lo,
           const float* __restrict__ attl1, const float* __restrict__ attr1,
           __hip_bfloat16* __restrict__ HXB1, float* __restrict__ AL1,
           float* __restrict__ AR1, int ntiles) {
    __shared__ union {
        unsigned short sidx[16 * SIS];   // 2176 B (phase 1)
        short hxs[16 * HXP];             // 4352 B (phase 2 output tile)
    } u;
    __shared__ short x1h[16 * HXP];      // 4352 B
    __shared__ short x1l[16 * HXP];      // 4352 B
    const int tid  = threadIdx.x;
    const int g    = tid >> 4;
    const int lt   = tid & 15;
    const int tile = blockIdx.x;

    // ---- phase 1: aggregate 16 nodes in one round, X1 -> LDS -------------
    {
        const int n = tile * 16 + g;
        const int h = lt >> 2;
        const float ar_h = AR0[(size_t)n * H + h];
        int2 cr = stage_idx16(g, lt, n, ssrc2u, deg, u.sidx);
        float a[8] = {0.f, 0.f, 0.f, 0.f, 0.f, 0.f, 0.f, 0.f};
        float ws = 0.f;
        gather16(g, lt, cr.x, cr.y, HXB0, AL0, ar_h, u.sidx, a, ws);
        float inv = 1.f / (ws + 1e-9f);
        const float4 b4a = *reinterpret_cast<const float4*>(b0 + 8 * lt);
        const float4 b4b = *reinterpret_cast<const float4*>(b0 + 8 * lt + 4);
        float bb[8] = {b4a.x, b4a.y, b4a.z, b4a.w, b4b.x, b4b.y, b4b.z, b4b.w};
        unsigned hw[4], lw[4];
#pragma unroll
        for (int k = 0; k < 4; ++k) {
            float o0 = fmaxf(a[2 * k] * inv + bb[2 * k], 0.f);
            float o1 = fmaxf(a[2 * k + 1] * inv + bb[2 * k + 1], 0.f);
            short h0 = f2bf(o0), h1 = f2bf(o1);
            short l0 = f2bf(o0 - bf2f(h0)), l1 = f2bf(o1 - bf2f(h1));
            hw[k] = (unsigned)(unsigned short)h0 | ((unsigned)(unsigned short)h1 << 16);
            lw[k] = (unsigned)(unsigned short)l0 | ((unsigned)(unsigned short)l1 << 16);
        }
        uint4 hv = {hw[0], hw[1], hw[2], hw[3]};
        uint4 lv = {lw[0], lw[1], lw[2], lw[3]};
        *reinterpret_cast<uint4*>(x1h + g * HXP + 8 * lt) = hv;
        *reinterpret_cast<uint4*>(x1l + g * HXP + 8 * lt) = lv;
    }
    __syncthreads();   // X1 tile complete; sidx dead from here (hxs aliases it)

    // ---- phase 2: layer-1 GEMM tile, A from LDS ---------------------------
    {
        const int wave = tid >> 6;
        const int lane = tid & 63;
        const int m    = lane & 15;
        const int q    = lane >> 4;
        const int q8   = q * 8;
        bf16x8 Bhi[2][4], Blo[2][4];
        bsetup_pre(W1hi, W1lo, wave, m, q8, Bhi, Blo);
        const float alw0  = attl1[wave * 32 + m];
        const float alw16 = attl1[wave * 32 + 16 + m];
        const float arw0  = attr1[wave * 32 + m];
        const float arw16 = attr1[wave * 32 + 16 + m];
        bf16x8 Ahi[4], Alo[4];
#pragma unroll
        for (int kc = 0; kc < 4; ++kc) {
            Ahi[kc] = *reinterpret_cast<const bf16x8*>(x1h + m * HXP + kc * 32 + q8);
            Alo[kc] = *reinterpret_cast<const bf16x8*>(x1l + m * HXP + kc * 32 + q8);
        }
        mfma_epi(tile, Ahi, Alo, Bhi, Blo, alw0, alw16, arw0, arw16,
                 u.hxs, AL1, AR1, wave, m, q);
    }
    __syncthreads();
    hxb_writeout(u.hxs, tile, HXB1);
}

// k_aggr1: layer-1 aggregation + head-mean (16-lane groups, inline-exp).
// Head grouping ((h0+h1)+(h2+h3)) via xor4 then xor8 — bit-exact.
__global__ __launch_bounds__(256)
void k_aggr1(const unsigned short* __restrict__ ssrc2u, const int* __restrict__ deg,
             const float* __restrict__ AL, const float* __restrict__ AR,
             const __hip_bfloat16* __restrict__ HXB, const float* __restrict__ bias,
             float* __restrict__ out, int N) {
    __shared__ unsigned short sidx[16 * SIS];   // 2176 B only
    const int tid = threadIdx.x;
    const int g   = tid >> 4;
    const int lt  = tid & 15;
    const int n   = blockIdx.x * 16 + g;   // N = 50000 = 3125*16, no tail
    const int h   = lt >> 2;
    const float ar_h = AR[(size_t)n * H + h];
    int2 cr = stage_idx16(g, lt, n, ssrc2u, deg, sidx);
    float a[8] = {0.f, 0.f, 0.f, 0.f, 0.f, 0.f, 0.f, 0.f};
    float ws = 0.f;
    gather16(g, lt, cr.x, cr.y, HXB, AL, ar_h, sidx, a, ws);
    float inv = 1.f / (ws + 1e-9f);
    float v[8];
#pragma unroll
    for (int k = 0; k < 8; ++k) {
        v[k] = a[k] * inv;
        v[k] += __shfl_xor(v[k], 4);    // h0+h1, h2+h3
        v[k] += __shfl_xor(v[k], 8);    // (h0+h1)+(h2+h3)
    }
    if (lt < 4) {
        const float4 b4a = *reinterpret_cast<const float4*>(bias + 8 * lt);
        const float4 b4b = *reinterpret_cast<const float4*>(bias + 8 * lt + 4);
        float4 o0, o1;
        o0.x = 0.25f * v[0] + b4a.x;
        o0.y = 0.25f * v[1] + b4a.y;
        o0.z = 0.25f * v[2] + b4a.z;
        o0.w = 0.25f * v[3] + b4a.w;
        o1.x = 0.25f * v[4] + b4b.x;
        o1.y = 0.25f * v[5] + b4b.y;
        o1.z = 0.25f * v[6] + b4b.z;
        o1.w = 0.25f * v[7] + b4b.w;
        *reinterpret_cast<float4*>(out + (size_t)n * D + 8 * lt)     = o0;
        *reinterpret_cast<float4*>(out + (size_t)n * D + 8 * lt + 4) = o1;
    }
}

// ===========================================================================
extern "C" void kernel_launch(void* const* d_in, const int* in_sizes, int n_in,
                              void* d_out, int out_size, void* d_ws, size_t ws_size,
                              hipStream_t stream) {
    const float* x     = (const float*)d_in[0];
    const int*   ei    = (const int*)d_in[1];
    const float* W0    = (const float*)d_in[2];
    const float* attl0 = (const float*)d_in[3];
    const float* attr0 = (const float*)d_in[4];
    const float* b0    = (const float*)d_in[5];
    const float* W1    = (const float*)d_in[6];
    const float* attl1 = (const float*)d_in[7];
    const float* attr1 = (const float*)d_in[8];
    const float* b1    = (const float*)d_in[9];

    const int N = in_sizes[0] / F;   // 50000
    const int E = in_sizes[1] / 2;   // 800000
    const int ntiles = N / 16;       // 3125

    // Workspace: HXB0 | HXB1 | W0hi | W0lo | W1hi | W1lo | AL0 | AR0 |
    //            AL1 | AR1 | ssrc2u (PADDED NBUCK*BUCKW nodes) | deg | buf | cntmat
    char* p = (char*)d_ws;
    __hip_bfloat16* HXB0 = (__hip_bfloat16*)p; p += (size_t)N * F * 2;
    __hip_bfloat16* HXB1 = (__hip_bfloat16*)p; p += (size_t)N * F * 2;
    short* W0hi = (short*)p;                   p += (size_t)F * F * 2;
    short* W0lo = (short*)p;                   p += (size_t)F * F * 2;
    short* W1hi = (short*)p;                   p += (size_t)F * F * 2;
    short* W1lo = (short*)p;                   p += (size_t)F * F * 2;
    float* AL0  = (float*)p;                   p += (size_t)N * H * 4;
    float* AR0  = (float*)p;                   p += (size_t)N * H * 4;
    float* AL1  = (float*)p;                   p += (size_t)N * H * 4;
    float* AR1  = (float*)p;                   p += (size_t)N * H * 4;
    unsigned short* ssrc2u = (unsigned short*)p;
    p += (size_t)NBUCK * BUCKW * MAXDEG * 2;   // padded: bucket writeout covers 50176 nodes
    int* deg = (int*)p;                        p += (size_t)N * 4;
    unsigned int* buf = (unsigned int*)p;      p += (size_t)NBUCK * NABLK * SEGCAP * 4;
    int* cntmat = (int*)p;                     // [NABLK][NBUCK]

    // k_init: bucketA (atomic-free) + W0/W1 pre-split
    k_init<<<NABLK + 8, 256, 0, stream>>>(ei, E, cntmat, buf,
                                          W0, W0hi, W0lo, W1, W1hi, W1lo);

    // k_mid: bucketB (256 blocks, overlapped) + gemm0 (2 tiles/block)
    k_mid<<<NBUCK + GB, 256, 0, stream>>>(buf, cntmat, deg, ssrc2u, N,
                                          x, W0hi, W0lo, attl0, attr0,
                                          HXB0, AL0, AR0, ntiles);

    // k_ag1: FUSED layer-0 aggregation (inline-exp, 13.1 KB LDS) + layer-1 GEMM
    k_ag1<<<ntiles, 256, 0, stream>>>(ssrc2u, deg, AL0, AR0, HXB0, b0,
                                      W1hi, W1lo, attl1, attr1,
                                      HXB1, AL1, AR1, ntiles);

    // layer-1 aggregation + head-mean (inline-exp)
    k_aggr1<<<ntiles, 256, 0, stream>>>(ssrc2u, deg, AL1, AR1, HXB1, b1,
                                        (float*)d_out, N);
}